// Round 8
// baseline (2029.016 us; speedup 1.0000x reference)
//
#include <hip/hip_runtime.h>
#include <hip/hip_bf16.h>

#define Bn   4096
#define Jn   17
#define Cn   512
#define Kn   3
#define TOKn 256
#define CHn  2048
#define EPSf 1e-5f
#define Mrows (Bn * Jn)          // 69632 GEMM rows

typedef unsigned short u16;
typedef short bf8_t __attribute__((ext_vector_type(8)));
typedef float f32x4 __attribute__((ext_vector_type(4)));

__device__ __forceinline__ float gelu_fast(float x) {
    float x2 = x * x;
    float z = x * __builtin_fmaf(0.1029474f, x2, 2.3022652f);
    float e = __builtin_amdgcn_exp2f(z);
    float r = __builtin_amdgcn_rcpf(e + 1.0f);
    return x * (1.0f - r);
}
__device__ __forceinline__ float bf2f(u16 u) {
    union { float f; unsigned int i; } w; w.i = ((unsigned int)u) << 16; return w.f;
}
__device__ __forceinline__ u16 f2bf(float f) {
    __hip_bfloat16 h = __float2bfloat16(f);
    union { __hip_bfloat16 h1; u16 u; } cv; cv.h1 = h; return cv.u;
}
__device__ __forceinline__ unsigned pk2(float a, float b) {
    float2 t; t.x = a; t.y = b;
    __hip_bfloat162 h = __float22bfloat162_rn(t);
    union { __hip_bfloat162 h2; unsigned u; } cv; cv.h2 = h; return cv.u;
}
__device__ __forceinline__ void unpack2(unsigned u, float& a, float& b) {
    union { float f; unsigned int i; } t;
    t.i = u << 16;          a = t.f;
    t.i = u & 0xffff0000u;  b = t.f;
}
__device__ __forceinline__ void gload_lds16(const void* g, void* l) {
    __builtin_amdgcn_global_load_lds(
        (const __attribute__((address_space(1))) void*)g,
        (__attribute__((address_space(3))) void*)l, 16, 0, 0);
}

// ---------------------------------------------------------------- prep
__global__ __launch_bounds__(256) void prep_kernel(
    const float* __restrict__ W21, const float* __restrict__ W22,
    const float* __restrict__ Wg1, const float* __restrict__ Wg2,
    const float* __restrict__ bg1, const float* __restrict__ bg2,
    const float* __restrict__ adj,
    const float* __restrict__ W11, const float* __restrict__ W12,
    u16* __restrict__ W21b, u16* __restrict__ W22b,
    u16* __restrict__ Wg1t, u16* __restrict__ Wg2t,
    float* __restrict__ bias2a, float* __restrict__ bias2b,
    u16* __restrict__ W11p, u16* __restrict__ W12p)
{
    int bid = blockIdx.x, tid = threadIdx.x;
    if (bid < 1024) {
        const float* src = (bid < 512) ? W21 : W22;
        u16* dst = (bid < 512) ? W21b : W22b;
        size_t base = (size_t)(bid & 511) * 2048 + (size_t)tid * 8;
        float4 v0 = *(const float4*)(src + base);
        float4 v1 = *(const float4*)(src + base + 4);
        uint4 o;
        o.x = pk2(v0.x, v0.y); o.y = pk2(v0.z, v0.w);
        o.z = pk2(v1.x, v1.y); o.w = pk2(v1.z, v1.w);
        *(uint4*)(dst + base) = o;
    } else if (bid < 2048) {
        const float* src = (bid < 1536) ? Wg1 : Wg2;
        u16* dst = (bid < 1536) ? Wg1t : Wg2t;
        int rbase = ((bid - 1024) & 511) * 3;
        int c = tid * 2;
        for (int rr = 0; rr < 3; ++rr) {
            int ro = rbase + rr;                  // over (k,o)
            int k = ro >> 9, o = ro & 511;
            const float* sp = src + ((size_t)k * Cn + o) * Cn + c;
            float2 v = *(const float2*)sp;
            *(unsigned*)(dst + (size_t)o * (Kn * Cn) + k * Cn + c) = pk2(v.x, v.y);
        }
    } else if (bid == 2048) {
        __shared__ float adjcs[Kn][Jn];
        for (int i = tid; i < Kn * Jn; i += 256) {
            int k = i / Jn, w = i - k * Jn;
            float s = 0.f;
            for (int v = 0; v < Jn; ++v) s += adj[k * (Jn * Jn) + v * Jn + w];
            adjcs[k][w] = s;
        }
        __syncthreads();
        for (int i = tid; i < Jn * Cn; i += 256) {
            int w = i >> 9, o = i & 511;
            float sa = 0.f, sb = 0.f;
            #pragma unroll
            for (int k = 0; k < Kn; ++k) {
                sa += bg1[k * Cn + o] * adjcs[k][w];
                sb += bg2[k * Cn + o] * adjcs[k][w];
            }
            bias2a[i] = sa; bias2b[i] = sb;
        }
    } else {
        // W11p: [ck(4)][t(256)][8] = W11[t][ck*8+e], zero-padded k>=17
        for (int i = tid; i < 4 * TOKn * 8; i += 256) {
            int ck = i >> 11, t = (i >> 3) & 255, e = i & 7;
            int k = ck * 8 + e;
            W11p[i] = (k < Jn) ? f2bf(W11[t * Jn + k]) : (u16)0;
        }
        // W12p [32][256] (pad j>=17 rows with 0)
        for (int idx = tid; idx < 32 * TOKn; idx += 256) {
            int j = idx >> 8, t = idx & 255;
            W12p[idx] = (j < Jn) ? f2bf(W12[j * TOKn + t]) : (u16)0;
        }
    }
}

// ---------------------------------------------------------------- premix: (optional LN1) + adjacency mix -> xmix[(b,w)][k*512+c] bf16
template<int STAGE>
__global__ __launch_bounds__(256) void premix_kernel(
    const float* __restrict__ x,          // stage1
    const u16* __restrict__ xn2,          // stage2
    const float* __restrict__ adj,
    const float* __restrict__ g1, const float* __restrict__ be1,
    float* __restrict__ mean1, float* __restrict__ rstd1,
    u16* __restrict__ xmix)
{
    __shared__ float xsh[Jn][Cn];
    __shared__ float coef[Kn][Jn][Jn];
    __shared__ float s0sh[Kn][Jn];
    __shared__ float s1sh[Kn][Jn];
    __shared__ float msh[Cn], rsh[Cn];
    int b = blockIdx.x, tid = threadIdx.x;

    for (int i = tid; i < Kn * Jn * Jn; i += 256) {
        int k = i / (Jn * Jn); int rem = i - k * (Jn * Jn);
        int v = rem / Jn; int w = rem - v * Jn;
        float av = adj[i];
        coef[k][w][v] = (STAGE == 1) ? av * g1[v] : av;
    }
    if (STAGE == 1) {
        const float* xp = x + (size_t)b * (Jn * Cn);
        for (int i = tid; i < (Jn * Cn) / 4; i += 256)
            ((float4*)&xsh[0][0])[i] = ((const float4*)xp)[i];
    } else {
        const u16* xp = xn2 + (size_t)b * (Jn * Cn);
        for (int i = tid; i < (Jn * Cn) / 8; i += 256) {
            uint4 u = ((const uint4*)xp)[i];
            float* d = &(&xsh[0][0])[i * 8];
            unpack2(u.x, d[0], d[1]); unpack2(u.y, d[2], d[3]);
            unpack2(u.z, d[4], d[5]); unpack2(u.w, d[6], d[7]);
        }
    }
    __syncthreads();
    if (STAGE == 1) {
        for (int c = tid; c < Cn; c += 256) {
            float s = 0.f, q = 0.f;
            #pragma unroll
            for (int v = 0; v < Jn; ++v) { float t = xsh[v][c]; s += t; q += t * t; }
            float m = s * (1.0f / Jn);
            float var = fmaxf(q * (1.0f / Jn) - m * m, 0.f);
            float r = rsqrtf(var + EPSf);
            msh[c] = m; rsh[c] = r;
            mean1[(size_t)b * Cn + c] = m;
            rstd1[(size_t)b * Cn + c] = r;
        }
    }
    if (tid < Kn * Jn) {
        int k = tid / Jn, w = tid - k * Jn;
        float s0 = 0.f, s1 = 0.f;
        #pragma unroll
        for (int v = 0; v < Jn; ++v) {
            if (STAGE == 1) s0 += adj[k * (Jn * Jn) + v * Jn + w] * be1[v];
            s1 += coef[k][w][v];
        }
        s0sh[k][w] = s0; s1sh[k][w] = s1;
    }
    __syncthreads();
    // vectorized: 2 consecutive c per thread -> u32 pk2 store
    u16* orow = xmix + (size_t)b * Jn * (Kn * Cn);
    int c = tid * 2;
    float m0v = 0.f, m1v = 0.f, r0v = 1.f, r1v = 1.f;
    if (STAGE == 1) { m0v = msh[c]; m1v = msh[c + 1]; r0v = rsh[c]; r1v = rsh[c + 1]; }
    for (int k = 0; k < Kn; ++k)
        for (int w = 0; w < Jn; ++w) {
            float cf[Jn];
            #pragma unroll
            for (int v = 0; v < Jn; ++v) cf[v] = coef[k][w][v];
            float d0 = 0.f, d1 = 0.f;
            #pragma unroll
            for (int v = 0; v < Jn; ++v) { d0 += cf[v] * xsh[v][c]; d1 += cf[v] * xsh[v][c + 1]; }
            float v0, v1;
            if (STAGE == 1) {
                float ss1 = s1sh[k][w], ss0 = s0sh[k][w];
                v0 = r0v * (d0 - m0v * ss1) + ss0;
                v1 = r1v * (d1 - m1v * ss1) + ss0;
            } else { v0 = d0; v1 = d1; }
            *(unsigned*)(orow + (size_t)w * (Kn * Cn) + k * Cn + c) = pk2(v0, v1);
        }
}

// ---------------------------------------------------------------- MLP1 (token mix) via MFMA (unchanged from R7)
__global__ __launch_bounds__(256) void mlp1_mfma(
    const float* __restrict__ x,
    const float* __restrict__ mean1, const float* __restrict__ rstd1,
    const float* __restrict__ g1, const float* __restrict__ be1,
    const u16* __restrict__ W11p,   // [4][256][8] bf16 padded, k-chunked
    const float* __restrict__ b11,
    const u16* __restrict__ W12p,   // [32][256] bf16 padded
    const float* __restrict__ b12,
    float* __restrict__ out)
{
    __shared__ __align__(16) u16 As[128 * 40];     // xn tile [c][j], stride 80B, swizzled
    __shared__ __align__(16) u16 Hs[128 * 128];    // hidden chunk [c][t], chunk-swizzled
    __shared__ __align__(16) u16 W11s[4 * TOKn * 8]; // [ck][t][8]
    __shared__ __align__(16) u16 W12s[32 * TOKn];
    __shared__ __align__(16) float b11s[TOKn];
    __shared__ __align__(16) float msrs[256];      // [0:128)=mean, [128:256)=rstd
    __shared__ float g1s[32], be1s[32];

    int tid = threadIdx.x;
    int lane = tid & 63, wave = tid >> 6;
    int b = blockIdx.y, c0 = blockIdx.x * 128;
    const float* xb = x + (size_t)b * (Jn * Cn);

    #pragma unroll
    for (int t = 0; t < 4; ++t) {
        int idx = t * 256 + tid;
        gload_lds16(W11p + idx * 8, (char*)W11s + idx * 16);
    }
    #pragma unroll
    for (int t = 0; t < 4; ++t) {
        int idx = t * 256 + tid;
        int j = idx >> 5, s = idx & 31;
        gload_lds16(W12p + j * TOKn + ((s ^ (j & 7)) << 3), (char*)W12s + idx * 16);
    }
    if (wave == 0) gload_lds16(b11 + lane * 4, (char*)b11s + lane * 16);
    if (wave == 1) {
        const float* src = (lane < 32) ? (mean1 + (size_t)b * Cn + c0 + lane * 4)
                                       : (rstd1 + (size_t)b * Cn + c0 + (lane - 32) * 4);
        gload_lds16(src, (char*)msrs + lane * 16);
    }
    if (tid < Jn) { g1s[tid] = g1[tid]; be1s[tid] = be1[tid]; }
    asm volatile("s_waitcnt vmcnt(0)" ::: "memory");
    __syncthreads();

    const float* ms = msrs;
    const float* rs = msrs + 128;
    #pragma unroll
    for (int it = 0; it < 8; ++it) {
        int idx = it * 256 + tid;
        int r = idx & 127, k = (idx >> 7) << 1;
        float mr = ms[r], rr = rs[r];
        float v0 = 0.f, v1 = 0.f;
        if (k < Jn)     v0 = (xb[(size_t)k * Cn + c0 + r] - mr) * rr * g1s[k] + be1s[k];
        if (k + 1 < Jn) v1 = (xb[(size_t)(k + 1) * Cn + c0 + r] - mr) * rr * g1s[k + 1] + be1s[k + 1];
        int ck = (k >> 3) ^ ((r >> 3) & 3);
        *(unsigned*)((char*)As + r * 80 + (ck << 4) + ((k & 7) << 1)) = pk2(v0, v1);
    }
    __syncthreads();

    int rb = wave * 32;
    f32x4 acc2[2][2];
    #pragma unroll
    for (int i = 0; i < 2; ++i)
        #pragma unroll
        for (int j = 0; j < 2; ++j) acc2[i][j] = (f32x4)0.f;

    bf8_t bfc[2];
    #pragma unroll
    for (int cf = 0; cf < 2; ++cf) {
        int c = rb + cf * 16 + (lane & 15);
        int ck = (lane >> 4) ^ ((c >> 3) & 3);
        bfc[cf] = *(const bf8_t*)((const char*)As + c * 80 + (ck << 4));
    }

    #pragma unroll
    for (int ch = 0; ch < 2; ++ch) {
        f32x4 acc1[8][2];
        #pragma unroll
        for (int tf = 0; tf < 8; ++tf)
            #pragma unroll
            for (int cf = 0; cf < 2; ++cf) acc1[tf][cf] = (f32x4)0.f;
        #pragma unroll
        for (int tf = 0; tf < 8; ++tf) {
            int t = ch * 128 + tf * 16 + (lane & 15);
            bf8_t aw = *(const bf8_t*)((const char*)W11s + ((lane >> 4) << 12) + t * 16);
            #pragma unroll
            for (int cf = 0; cf < 2; ++cf)
                acc1[tf][cf] = __builtin_amdgcn_mfma_f32_16x16x32_bf16(aw, bfc[cf], acc1[tf][cf], 0, 0, 0);
        }
        #pragma unroll
        for (int tf = 0; tf < 8; ++tf) {
            int t0 = tf * 16 + ((lane >> 4) << 2);
            float bq0 = b11s[ch * 128 + t0 + 0];
            float bq1 = b11s[ch * 128 + t0 + 1];
            float bq2 = b11s[ch * 128 + t0 + 2];
            float bq3 = b11s[ch * 128 + t0 + 3];
            #pragma unroll
            for (int cf = 0; cf < 2; ++cf) {
                int c = rb + cf * 16 + (lane & 15);
                float h0 = gelu_fast(acc1[tf][cf][0] + bq0);
                float h1 = gelu_fast(acc1[tf][cf][1] + bq1);
                float h2 = gelu_fast(acc1[tf][cf][2] + bq2);
                float h3 = gelu_fast(acc1[tf][cf][3] + bq3);
                uint2 w; w.x = pk2(h0, h1); w.y = pk2(h2, h3);
                *(uint2*)((char*)Hs + c * 256 + ((((t0 >> 3) ^ (c & 7))) << 4) + ((t0 & 7) << 1)) = w;
            }
        }
        #pragma unroll
        for (int kt = 0; kt < 4; ++kt) {
            bf8_t bh[2];
            #pragma unroll
            for (int cf = 0; cf < 2; ++cf) {
                int c = rb + cf * 16 + (lane & 15);
                int tc = kt * 4 + (lane >> 4);
                bh[cf] = *(const bf8_t*)((const char*)Hs + c * 256 + ((tc ^ (c & 7)) << 4));
            }
            #pragma unroll
            for (int jf = 0; jf < 2; ++jf) {
                int j = jf * 16 + (lane & 15);
                int tc = ch * 16 + kt * 4 + (lane >> 4);
                bf8_t aw = *(const bf8_t*)((const char*)W12s + j * 512 + ((tc ^ (j & 7)) << 4));
                #pragma unroll
                for (int cf = 0; cf < 2; ++cf)
                    acc2[jf][cf] = __builtin_amdgcn_mfma_f32_16x16x32_bf16(aw, bh[cf], acc2[jf][cf], 0, 0, 0);
            }
        }
    }

    #pragma unroll
    for (int jf = 0; jf < 2; ++jf) {
        #pragma unroll
        for (int cf = 0; cf < 2; ++cf) {
            int c = c0 + rb + cf * 16 + (lane & 15);
            #pragma unroll
            for (int i = 0; i < 4; ++i) {
                int j = jf * 16 + ((lane >> 4) << 2) + i;
                if (j < Jn) {
                    size_t off = (size_t)b * (Jn * Cn) + (size_t)j * Cn + c;
                    out[off] = x[off] + acc2[jf][cf][i] + b12[j];
                }
            }
        }
    }
}

// ---------------------------------------------------------------- LN2 over C per (b,j) row; writes xn2 bf16
__global__ __launch_bounds__(256) void ln2_kernel(const float* __restrict__ X2,
        const float* __restrict__ g2, const float* __restrict__ be2,
        u16* __restrict__ xn2)
{
    int row = blockIdx.x * 4 + (threadIdx.x >> 6);
    int lane = threadIdx.x & 63;
    const float* p = X2 + (size_t)row * Cn;
    float4 v0 = ((const float4*)p)[lane];
    float4 v1 = ((const float4*)p)[lane + 64];
    float s = v0.x + v0.y + v0.z + v0.w + v1.x + v1.y + v1.z + v1.w;
    float q = v0.x*v0.x + v0.y*v0.y + v0.z*v0.z + v0.w*v0.w
            + v1.x*v1.x + v1.y*v1.y + v1.z*v1.z + v1.w*v1.w;
    #pragma unroll
    for (int off = 32; off > 0; off >>= 1) { s += __shfl_xor(s, off); q += __shfl_xor(q, off); }
    float mean = s * (1.0f / Cn);
    float var = fmaxf(q * (1.0f / Cn) - mean * mean, 0.f);
    float rs = rsqrtf(var + EPSf);
    float4 ga = ((const float4*)g2)[lane],      ba = ((const float4*)be2)[lane];
    float4 gb = ((const float4*)g2)[lane + 64], bb = ((const float4*)be2)[lane + 64];
    uint2 w0, w1;
    w0.x = pk2((v0.x-mean)*rs*ga.x + ba.x, (v0.y-mean)*rs*ga.y + ba.y);
    w0.y = pk2((v0.z-mean)*rs*ga.z + ba.z, (v0.w-mean)*rs*ga.w + ba.w);
    w1.x = pk2((v1.x-mean)*rs*gb.x + bb.x, (v1.y-mean)*rs*gb.y + bb.y);
    w1.y = pk2((v1.z-mean)*rs*gb.z + bb.z, (v1.w-mean)*rs*gb.w + bb.w);
    ((uint2*)(xn2 + (size_t)row * Cn))[lane] = w0;
    ((uint2*)(xn2 + (size_t)row * Cn))[lane + 64] = w1;
}

// ---------------------------------------------------------------- MFMA GEMM: C(M x N) = A(M x K) * Bt(N x K)^T
// 256x256 tile, 8 waves (2M x 4N), 512 threads. 4-slot LDS ring per matrix at
// k-slice (=32) granularity; prefetch distance 3; counted vmcnt (12/8/4/0) so
// loads stay in flight across barriers (raw s_barrier, no __syncthreads drain).
// 32 MFMA per wave between barriers; setprio around the MFMA cluster.
// EPI 0: outH = bf16(gelu(acc + bias[col]))
// EPI 1: outF += acc + (bias ? bias[col] : 0)
// EPI 2: outF += acc + bias[(row%17)*512+col]
template<int EPI>
__global__ __launch_bounds__(512) void gemm_bt(
    const u16* __restrict__ A, int ldA,
    const u16* __restrict__ Bt, int ldB,
    int K, int Nld,
    const float* __restrict__ bias,
    float* __restrict__ outF, u16* __restrict__ outH)
{
    __shared__ __align__(16) u16 As[4 * 8192];   // 4 slots x (256 rows x 32 k) = 64 KB
    __shared__ __align__(16) u16 Bs[4 * 8192];   // 64 KB

    int tid = threadIdx.x;
    int gx = gridDim.x;
    int total = gx * gridDim.y;
    int lid = blockIdx.y * gx + blockIdx.x;
    int cpx = total >> 3;
    int wg = (lid & 7) * cpx + (lid >> 3);       // XCD-chunked remap (total % 8 == 0)
    int n0 = (wg % gx) << 8;
    int m0 = (wg / gx) << 8;

    int wave = tid >> 6, lane = tid & 63;
    int wr = wave >> 2, wc = wave & 3;           // 2M x 4N
    int q = lane >> 4, li = lane & 15;

    // ---- staging addresses (2 chunk-loads per matrix per slice per thread)
    int idxs[2] = { tid, 512 + tid };
    const u16* aP[2]; const u16* bP[2];
    char* aL[2]; char* bL[2];
    #pragma unroll
    for (int p = 0; p < 2; ++p) {
        int r = idxs[p] >> 2, cq = idxs[p] & 3;
        int sw = ((cq ^ (r & 3)) << 3);          // pre-swizzled global k-chunk (elements)
        aP[p] = A  + (size_t)(m0 + r) * ldA + sw;
        bP[p] = Bt + (size_t)(n0 + r) * ldB + sw;
        aL[p] = (char*)As + idxs[p] * 16;
        bL[p] = (char*)Bs + idxs[p] * 16;
    }

    // ---- fragment LDS byte offsets (within a slot)
    int aByte[8], bByte[4];
    #pragma unroll
    for (int m = 0; m < 8; ++m) {
        int row = wr * 128 + m * 16 + li;
        aByte[m] = row * 64 + ((q ^ (row & 3)) << 4);
    }
    #pragma unroll
    for (int n = 0; n < 4; ++n) {
        int row = wc * 64 + n * 16 + li;
        bByte[n] = row * 64 + ((q ^ (row & 3)) << 4);
    }

    f32x4 acc[8][4];
    #pragma unroll
    for (int m = 0; m < 8; ++m)
        #pragma unroll
        for (int n = 0; n < 4; ++n) acc[m][n] = (f32x4)0.f;

    int NS = K >> 5;                             // k-slices of 32
    // prologue: slices 0..2 into slots 0..2 (12 loads/thread)
    #pragma unroll
    for (int sl = 0; sl < 3; ++sl) {
        int slot = sl, k0 = sl << 5;
        #pragma unroll
        for (int p = 0; p < 2; ++p) {
            gload_lds16(aP[p] + k0, aL[p] + slot * 16384);
            gload_lds16(bP[p] + k0, bL[p] + slot * 16384);
        }
    }

    for (int s = 0; s < NS; ++s) {
        if (s + 3 < NS) {                        // prefetch slice s+3 (slot free: last read s-1)
            int slot = (s + 3) & 3, k0 = (s + 3) << 5;
            #pragma unroll
            for (int p = 0; p < 2; ++p) {
                gload_lds16(aP[p] + k0, aL[p] + slot * 16384);
                gload_lds16(bP[p] + k0, bL[p] + slot * 16384);
            }
        }
        int rem = NS - 1 - s;                    // counted vmcnt: wait slice s only
        if (rem >= 3)      asm volatile("s_waitcnt vmcnt(12)" ::: "memory");
        else if (rem == 2) asm volatile("s_waitcnt vmcnt(8)" ::: "memory");
        else if (rem == 1) asm volatile("s_waitcnt vmcnt(4)" ::: "memory");
        else               asm volatile("s_waitcnt vmcnt(0)" ::: "memory");
        asm volatile("s_barrier" ::: "memory");

        const char* aBase = (const char*)As + (s & 3) * 16384;
        const char* bBase = (const char*)Bs + (s & 3) * 16384;
        bf8_t af[8], bfv[4];
        #pragma unroll
        for (int m = 0; m < 8; ++m) af[m] = *(const bf8_t*)(aBase + aByte[m]);
        #pragma unroll
        for (int n = 0; n < 4; ++n) bfv[n] = *(const bf8_t*)(bBase + bByte[n]);
        __builtin_amdgcn_s_setprio(1);
        #pragma unroll
        for (int m = 0; m < 8; ++m)
            #pragma unroll
            for (int n = 0; n < 4; ++n)
                acc[m][n] = __builtin_amdgcn_mfma_f32_16x16x32_bf16(af[m], bfv[n], acc[m][n], 0, 0, 0);
        __builtin_amdgcn_s_setprio(0);
        __builtin_amdgcn_sched_barrier(0);       // pin MFMAs above the closing barrier
        asm volatile("s_waitcnt lgkmcnt(0)" ::: "memory");
        asm volatile("s_barrier" ::: "memory");  // all waves done reading slot s -> reusable
    }

    // ---- epilogue
    #pragma unroll
    for (int m = 0; m < 8; ++m) {
        int rbase = m0 + wr * 128 + m * 16 + ((lane >> 4) << 2);
        #pragma unroll
        for (int n = 0; n < 4; ++n) {
            int col = n0 + wc * 64 + n * 16 + li;
            if (EPI == 0) {
                float bv = bias[col];
                #pragma unroll
                for (int i = 0; i < 4; ++i) {
                    float v = gelu_fast(acc[m][n][i] + bv);
                    outH[(size_t)(rbase + i) * Nld + col] = f2bf(v);
                }
            } else if (EPI == 1) {
                float bv = bias ? bias[col] : 0.f;
                #pragma unroll
                for (int i = 0; i < 4; ++i) {
                    size_t off = (size_t)(rbase + i) * Nld + col;
                    outF[off] += acc[m][n][i] + bv;
                }
            } else {
                #pragma unroll
                for (int i = 0; i < 4; ++i) {
                    int row = rbase + i;
                    int w = row % Jn;
                    size_t off = (size_t)row * Nld + col;
                    outF[off] += acc[m][n][i] + bias[w * Cn + col];
                }
            }
        }
    }
}

// ----------------------------------------------------------------
extern "C" void kernel_launch(void* const* d_in, const int* in_sizes, int n_in,
                              void* d_out, int out_size, void* d_ws, size_t ws_size,
                              hipStream_t stream)
{
    (void)in_sizes; (void)n_in; (void)out_size;
    const float* x   = (const float*)d_in[0];
    const float* adj = (const float*)d_in[1];
    const float* g1  = (const float*)d_in[2];
    const float* be1 = (const float*)d_in[3];
    const float* g2  = (const float*)d_in[4];
    const float* be2 = (const float*)d_in[5];
    const float* Wg1 = (const float*)d_in[6];
    const float* bg1 = (const float*)d_in[7];
    const float* Wg2 = (const float*)d_in[8];
    const float* bg2 = (const float*)d_in[9];
    const float* W11 = (const float*)d_in[10];
    const float* b11 = (const float*)d_in[11];
    const float* W12 = (const float*)d_in[12];
    const float* b12 = (const float*)d_in[13];
    const float* W21 = (const float*)d_in[14];
    const float* b21 = (const float*)d_in[15];
    const float* W22 = (const float*)d_in[16];
    const float* b22 = (const float*)d_in[17];
    float* out = (float*)d_out;

    char* p = (char*)d_ws;
    float* mean1  = (float*)p;                 p += (size_t)Bn * Cn * 4;
    float* rstd1  = (float*)p;                 p += (size_t)Bn * Cn * 4;
    u16*   xn2    = (u16*)p;                   p += (size_t)Mrows * Cn * 2;
    u16*   W21b   = (u16*)p;                   p += (size_t)CHn * Cn * 2;
    u16*   W22b   = (u16*)p;                   p += (size_t)CHn * Cn * 2;
    u16*   Wg1t   = (u16*)p;                   p += (size_t)Cn * Kn * Cn * 2;
    u16*   Wg2t   = (u16*)p;                   p += (size_t)Cn * Kn * Cn * 2;
    float* bias2a = (float*)p;                 p += (size_t)Jn * Cn * 4;
    float* bias2b = (float*)p;                 p += (size_t)Jn * Cn * 4;
    u16*   W11p   = (u16*)p;                   p += (size_t)4 * TOKn * 8 * 2;
    u16*   W12p   = (u16*)p;                   p += (size_t)32 * TOKn * 2;
    u16*   xmix   = (u16*)p;                   // shared with H
    u16*   Hbuf   = xmix;

    size_t fixedBytes = (size_t)((char*)xmix - (char*)d_ws);
    bool fullH = ws_size >= fixedBytes + (size_t)Mrows * CHn * 2;

    prep_kernel<<<2050, 256, 0, stream>>>(W21, W22, Wg1, Wg2, bg1, bg2, adj, W11, W12,
                                          W21b, W22b, Wg1t, Wg2t, bias2a, bias2b, W11p, W12p);
    // stage 1
    premix_kernel<1><<<Bn, 256, 0, stream>>>(x, (const u16*)nullptr, adj, g1, be1, mean1, rstd1, xmix);
    {
        dim3 g(Cn / 128, Bn);
        mlp1_mfma<<<g, 256, 0, stream>>>(x, mean1, rstd1, g1, be1, W11p, b11, W12p, b12, out);
    }
    {
        dim3 g(Cn / 256, Mrows / 256);     // N-fast
        gemm_bt<2><<<g, 512, 0, stream>>>(xmix, Kn * Cn, Wg1t, Kn * Cn, Kn * Cn, Cn, bias2a, out, (u16*)nullptr);
    }
    // stage 2
    ln2_kernel<<<Mrows / 4, 256, 0, stream>>>(out, g2, be2, xn2);
    if (fullH) {
        dim3 ga(CHn / 256, Mrows / 256);
        gemm_bt<0><<<ga, 512, 0, stream>>>(xn2, Cn, W21b, Cn, Cn, CHn, b21, (float*)nullptr, Hbuf);
        dim3 gb(Cn / 256, Mrows / 256);
        gemm_bt<1><<<gb, 512, 0, stream>>>(Hbuf, CHn, W22b, CHn, CHn, Cn, b22, out, (u16*)nullptr);
    } else {
        for (int h = 0; h < 2; ++h) {
            int hc = h * 1024;
            dim3 ga(1024 / 256, Mrows / 256);
            gemm_bt<0><<<ga, 512, 0, stream>>>(xn2, Cn, W21b + (size_t)hc * Cn, Cn, Cn, 1024, b21 + hc, (float*)nullptr, Hbuf);
            dim3 gb(Cn / 256, Mrows / 256);
            gemm_bt<1><<<gb, 512, 0, stream>>>(Hbuf, 1024, W22b + hc, CHn, 1024, Cn, (h == 0) ? b22 : (const float*)nullptr, out, (u16*)nullptr);
        }
    }
    premix_kernel<2><<<Bn, 256, 0, stream>>>((const float*)nullptr, xn2, adj, (const float*)nullptr, (const float*)nullptr,
                                             (float*)nullptr, (float*)nullptr, xmix);
    {
        dim3 g(Cn / 256, Mrows / 256);
        gemm_bt<2><<<g, 512, 0, stream>>>(xmix, Kn * Cn, Wg2t, Kn * Cn, Kn * Cn, Cn, bias2b, out, (u16*)nullptr);
    }
}

// Round 9
// 1635.688 us; speedup vs baseline: 1.2405x; 1.2405x over previous
//
#include <hip/hip_runtime.h>
#include <hip/hip_bf16.h>

#define Bn   4096
#define Jn   17
#define Cn   512
#define Kn   3
#define TOKn 256
#define CHn  2048
#define EPSf 1e-5f
#define Mrows (Bn * Jn)          // 69632 GEMM rows
#define KCAT (CHn + Kn * Cn)     // 3584 combined K

typedef unsigned short u16;
typedef short bf8_t __attribute__((ext_vector_type(8)));
typedef float f32x4 __attribute__((ext_vector_type(4)));

__device__ __forceinline__ float gelu_fast(float x) {
    float x2 = x * x;
    float z = x * __builtin_fmaf(0.1029474f, x2, 2.3022652f);
    float e = __builtin_amdgcn_exp2f(z);
    float r = __builtin_amdgcn_rcpf(e + 1.0f);
    return x * (1.0f - r);
}
__device__ __forceinline__ float bf2f(u16 u) {
    union { float f; unsigned int i; } w; w.i = ((unsigned int)u) << 16; return w.f;
}
__device__ __forceinline__ u16 f2bf(float f) {
    __hip_bfloat16 h = __float2bfloat16(f);
    union { __hip_bfloat16 h1; u16 u; } cv; cv.h1 = h; return cv.u;
}
__device__ __forceinline__ unsigned pk2(float a, float b) {
    float2 t; t.x = a; t.y = b;
    __hip_bfloat162 h = __float22bfloat162_rn(t);
    union { __hip_bfloat162 h2; unsigned u; } cv; cv.h2 = h; return cv.u;
}
__device__ __forceinline__ void unpack2(unsigned u, float& a, float& b) {
    union { float f; unsigned int i; } t;
    t.i = u << 16;          a = t.f;
    t.i = u & 0xffff0000u;  b = t.f;
}
__device__ __forceinline__ void gload_lds16(const void* g, void* l) {
    __builtin_amdgcn_global_load_lds(
        (const __attribute__((address_space(1))) void*)g,
        (__attribute__((address_space(3))) void*)l, 16, 0, 0);
}

// ---------------------------------------------------------------- prep
__global__ __launch_bounds__(256) void prep_kernel(
    const float* __restrict__ W21, const float* __restrict__ W22,
    const float* __restrict__ Wg1, const float* __restrict__ Wg2,
    const float* __restrict__ bg1, const float* __restrict__ bg2,
    const float* __restrict__ adj,
    const float* __restrict__ W11, const float* __restrict__ W12,
    const float* __restrict__ b22,
    u16* __restrict__ W21b, u16* __restrict__ W22b,
    u16* __restrict__ Wg1t, u16* __restrict__ Wg2t,
    float* __restrict__ bias2a, float* __restrict__ bias2b, float* __restrict__ bias2bc,
    u16* __restrict__ W11p, u16* __restrict__ W12p,
    u16* __restrict__ Wcomb)
{
    int bid = blockIdx.x, tid = threadIdx.x;
    if (bid < 1024) {
        const float* src = (bid < 512) ? W21 : W22;
        u16* dst = (bid < 512) ? W21b : W22b;
        size_t base = (size_t)(bid & 511) * 2048 + (size_t)tid * 8;
        float4 v0 = *(const float4*)(src + base);
        float4 v1 = *(const float4*)(src + base + 4);
        uint4 o;
        o.x = pk2(v0.x, v0.y); o.y = pk2(v0.z, v0.w);
        o.z = pk2(v1.x, v1.y); o.w = pk2(v1.z, v1.w);
        *(uint4*)(dst + base) = o;
    } else if (bid < 2048) {
        const float* src = (bid < 1536) ? Wg1 : Wg2;
        u16* dst = (bid < 1536) ? Wg1t : Wg2t;
        int rbase = ((bid - 1024) & 511) * 3;
        int c = tid * 2;
        for (int rr = 0; rr < 3; ++rr) {
            int ro = rbase + rr;                  // over (k,o)
            int k = ro >> 9, o = ro & 511;
            const float* sp = src + ((size_t)k * Cn + o) * Cn + c;
            float2 v = *(const float2*)sp;
            *(unsigned*)(dst + (size_t)o * (Kn * Cn) + k * Cn + c) = pk2(v.x, v.y);
        }
    } else if (bid == 2048) {
        __shared__ float adjcs[Kn][Jn];
        for (int i = tid; i < Kn * Jn; i += 256) {
            int k = i / Jn, w = i - k * Jn;
            float s = 0.f;
            for (int v = 0; v < Jn; ++v) s += adj[k * (Jn * Jn) + v * Jn + w];
            adjcs[k][w] = s;
        }
        __syncthreads();
        for (int i = tid; i < Jn * Cn; i += 256) {
            int w = i >> 9, o = i & 511;
            float sa = 0.f, sb = 0.f;
            #pragma unroll
            for (int k = 0; k < Kn; ++k) {
                sa += bg1[k * Cn + o] * adjcs[k][w];
                sb += bg2[k * Cn + o] * adjcs[k][w];
            }
            bias2a[i] = sa; bias2b[i] = sb; bias2bc[i] = sb + b22[o];
        }
    } else if (bid == 2049) {
        // W11p: [ck(4)][t(256)][8] = W11[t][ck*8+e], zero-padded k>=17
        for (int i = tid; i < 4 * TOKn * 8; i += 256) {
            int ck = i >> 11, t = (i >> 3) & 255, e = i & 7;
            int k = ck * 8 + e;
            W11p[i] = (k < Jn) ? f2bf(W11[t * Jn + k]) : (u16)0;
        }
        // W12p [32][256] (pad j>=17 rows with 0)
        for (int idx = tid; idx < 32 * TOKn; idx += 256) {
            int j = idx >> 8, t = idx & 255;
            W12p[idx] = (j < Jn) ? f2bf(W12[j * TOKn + t]) : (u16)0;
        }
    } else {
        // Wcomb row o: [0,2048) = W22[o][:], [2048,3584) = Wg2[k][o][c]
        int o = bid - 2050;
        for (int idx = tid; idx < KCAT; idx += 256) {
            float v;
            if (idx < CHn) v = W22[(size_t)o * CHn + idx];
            else {
                int rem = idx - CHn;
                int k = rem >> 9, c = rem & 511;
                v = Wg2[((size_t)k * Cn + o) * Cn + c];
            }
            Wcomb[(size_t)o * KCAT + idx] = f2bf(v);
        }
    }
}

// ---------------------------------------------------------------- premix: (optional LN1) + adjacency mix -> dst[row][k*512+c] bf16
// row = b*17 + w, row stride oStride, column offset oColOff.
template<int STAGE>
__global__ __launch_bounds__(256) void premix_kernel(
    const float* __restrict__ x,          // stage1
    const u16* __restrict__ xn2,          // stage2
    const float* __restrict__ adj,
    const float* __restrict__ g1, const float* __restrict__ be1,
    float* __restrict__ mean1, float* __restrict__ rstd1,
    u16* __restrict__ xmix, int oStride, int oColOff)
{
    __shared__ float xsh[Jn][Cn];
    __shared__ float coef[Kn][Jn][Jn];
    __shared__ float s0sh[Kn][Jn];
    __shared__ float s1sh[Kn][Jn];
    __shared__ float msh[Cn], rsh[Cn];
    int b = blockIdx.x, tid = threadIdx.x;

    for (int i = tid; i < Kn * Jn * Jn; i += 256) {
        int k = i / (Jn * Jn); int rem = i - k * (Jn * Jn);
        int v = rem / Jn; int w = rem - v * Jn;
        float av = adj[i];
        coef[k][w][v] = (STAGE == 1) ? av * g1[v] : av;
    }
    if (STAGE == 1) {
        const float* xp = x + (size_t)b * (Jn * Cn);
        for (int i = tid; i < (Jn * Cn) / 4; i += 256)
            ((float4*)&xsh[0][0])[i] = ((const float4*)xp)[i];
    } else {
        const u16* xp = xn2 + (size_t)b * (Jn * Cn);
        for (int i = tid; i < (Jn * Cn) / 8; i += 256) {
            uint4 u = ((const uint4*)xp)[i];
            float* d = &(&xsh[0][0])[i * 8];
            unpack2(u.x, d[0], d[1]); unpack2(u.y, d[2], d[3]);
            unpack2(u.z, d[4], d[5]); unpack2(u.w, d[6], d[7]);
        }
    }
    __syncthreads();
    if (STAGE == 1) {
        for (int c = tid; c < Cn; c += 256) {
            float s = 0.f, q = 0.f;
            #pragma unroll
            for (int v = 0; v < Jn; ++v) { float t = xsh[v][c]; s += t; q += t * t; }
            float m = s * (1.0f / Jn);
            float var = fmaxf(q * (1.0f / Jn) - m * m, 0.f);
            float r = rsqrtf(var + EPSf);
            msh[c] = m; rsh[c] = r;
            mean1[(size_t)b * Cn + c] = m;
            rstd1[(size_t)b * Cn + c] = r;
        }
    }
    if (tid < Kn * Jn) {
        int k = tid / Jn, w = tid - k * Jn;
        float s0 = 0.f, s1 = 0.f;
        #pragma unroll
        for (int v = 0; v < Jn; ++v) {
            if (STAGE == 1) s0 += adj[k * (Jn * Jn) + v * Jn + w] * be1[v];
            s1 += coef[k][w][v];
        }
        s0sh[k][w] = s0; s1sh[k][w] = s1;
    }
    __syncthreads();
    // vectorized: 2 consecutive c per thread -> u32 pk2 store
    u16* orow = xmix + (size_t)b * Jn * oStride + oColOff;
    int c = tid * 2;
    float m0v = 0.f, m1v = 0.f, r0v = 1.f, r1v = 1.f;
    if (STAGE == 1) { m0v = msh[c]; m1v = msh[c + 1]; r0v = rsh[c]; r1v = rsh[c + 1]; }
    for (int k = 0; k < Kn; ++k)
        for (int w = 0; w < Jn; ++w) {
            float cf[Jn];
            #pragma unroll
            for (int v = 0; v < Jn; ++v) cf[v] = coef[k][w][v];
            float d0 = 0.f, d1 = 0.f;
            #pragma unroll
            for (int v = 0; v < Jn; ++v) { d0 += cf[v] * xsh[v][c]; d1 += cf[v] * xsh[v][c + 1]; }
            float v0, v1;
            if (STAGE == 1) {
                float ss1 = s1sh[k][w], ss0 = s0sh[k][w];
                v0 = r0v * (d0 - m0v * ss1) + ss0;
                v1 = r1v * (d1 - m1v * ss1) + ss0;
            } else { v0 = d0; v1 = d1; }
            *(unsigned*)(orow + (size_t)w * oStride + k * Cn + c) = pk2(v0, v1);
        }
}

// ---------------------------------------------------------------- MLP1 (token mix) via MFMA (unchanged from R7)
__global__ __launch_bounds__(256) void mlp1_mfma(
    const float* __restrict__ x,
    const float* __restrict__ mean1, const float* __restrict__ rstd1,
    const float* __restrict__ g1, const float* __restrict__ be1,
    const u16* __restrict__ W11p,   // [4][256][8] bf16 padded, k-chunked
    const float* __restrict__ b11,
    const u16* __restrict__ W12p,   // [32][256] bf16 padded
    const float* __restrict__ b12,
    float* __restrict__ out)
{
    __shared__ __align__(16) u16 As[128 * 40];     // xn tile [c][j], stride 80B, swizzled
    __shared__ __align__(16) u16 Hs[128 * 128];    // hidden chunk [c][t], chunk-swizzled
    __shared__ __align__(16) u16 W11s[4 * TOKn * 8]; // [ck][t][8]
    __shared__ __align__(16) u16 W12s[32 * TOKn];
    __shared__ __align__(16) float b11s[TOKn];
    __shared__ __align__(16) float msrs[256];      // [0:128)=mean, [128:256)=rstd
    __shared__ float g1s[32], be1s[32];

    int tid = threadIdx.x;
    int lane = tid & 63, wave = tid >> 6;
    int b = blockIdx.y, c0 = blockIdx.x * 128;
    const float* xb = x + (size_t)b * (Jn * Cn);

    #pragma unroll
    for (int t = 0; t < 4; ++t) {
        int idx = t * 256 + tid;
        gload_lds16(W11p + idx * 8, (char*)W11s + idx * 16);
    }
    #pragma unroll
    for (int t = 0; t < 4; ++t) {
        int idx = t * 256 + tid;
        int j = idx >> 5, s = idx & 31;
        gload_lds16(W12p + j * TOKn + ((s ^ (j & 7)) << 3), (char*)W12s + idx * 16);
    }
    if (wave == 0) gload_lds16(b11 + lane * 4, (char*)b11s + lane * 16);
    if (wave == 1) {
        const float* src = (lane < 32) ? (mean1 + (size_t)b * Cn + c0 + lane * 4)
                                       : (rstd1 + (size_t)b * Cn + c0 + (lane - 32) * 4);
        gload_lds16(src, (char*)msrs + lane * 16);
    }
    if (tid < Jn) { g1s[tid] = g1[tid]; be1s[tid] = be1[tid]; }
    asm volatile("s_waitcnt vmcnt(0)" ::: "memory");
    __syncthreads();

    const float* ms = msrs;
    const float* rs = msrs + 128;
    #pragma unroll
    for (int it = 0; it < 8; ++it) {
        int idx = it * 256 + tid;
        int r = idx & 127, k = (idx >> 7) << 1;
        float mr = ms[r], rr = rs[r];
        float v0 = 0.f, v1 = 0.f;
        if (k < Jn)     v0 = (xb[(size_t)k * Cn + c0 + r] - mr) * rr * g1s[k] + be1s[k];
        if (k + 1 < Jn) v1 = (xb[(size_t)(k + 1) * Cn + c0 + r] - mr) * rr * g1s[k + 1] + be1s[k + 1];
        int ck = (k >> 3) ^ ((r >> 3) & 3);
        *(unsigned*)((char*)As + r * 80 + (ck << 4) + ((k & 7) << 1)) = pk2(v0, v1);
    }
    __syncthreads();

    int rb = wave * 32;
    f32x4 acc2[2][2];
    #pragma unroll
    for (int i = 0; i < 2; ++i)
        #pragma unroll
        for (int j = 0; j < 2; ++j) acc2[i][j] = (f32x4)0.f;

    bf8_t bfc[2];
    #pragma unroll
    for (int cf = 0; cf < 2; ++cf) {
        int c = rb + cf * 16 + (lane & 15);
        int ck = (lane >> 4) ^ ((c >> 3) & 3);
        bfc[cf] = *(const bf8_t*)((const char*)As + c * 80 + (ck << 4));
    }

    #pragma unroll
    for (int ch = 0; ch < 2; ++ch) {
        f32x4 acc1[8][2];
        #pragma unroll
        for (int tf = 0; tf < 8; ++tf)
            #pragma unroll
            for (int cf = 0; cf < 2; ++cf) acc1[tf][cf] = (f32x4)0.f;
        #pragma unroll
        for (int tf = 0; tf < 8; ++tf) {
            int t = ch * 128 + tf * 16 + (lane & 15);
            bf8_t aw = *(const bf8_t*)((const char*)W11s + ((lane >> 4) << 12) + t * 16);
            #pragma unroll
            for (int cf = 0; cf < 2; ++cf)
                acc1[tf][cf] = __builtin_amdgcn_mfma_f32_16x16x32_bf16(aw, bfc[cf], acc1[tf][cf], 0, 0, 0);
        }
        #pragma unroll
        for (int tf = 0; tf < 8; ++tf) {
            int t0 = tf * 16 + ((lane >> 4) << 2);
            float bq0 = b11s[ch * 128 + t0 + 0];
            float bq1 = b11s[ch * 128 + t0 + 1];
            float bq2 = b11s[ch * 128 + t0 + 2];
            float bq3 = b11s[ch * 128 + t0 + 3];
            #pragma unroll
            for (int cf = 0; cf < 2; ++cf) {
                int c = rb + cf * 16 + (lane & 15);
                float h0 = gelu_fast(acc1[tf][cf][0] + bq0);
                float h1 = gelu_fast(acc1[tf][cf][1] + bq1);
                float h2 = gelu_fast(acc1[tf][cf][2] + bq2);
                float h3 = gelu_fast(acc1[tf][cf][3] + bq3);
                uint2 w; w.x = pk2(h0, h1); w.y = pk2(h2, h3);
                *(uint2*)((char*)Hs + c * 256 + ((((t0 >> 3) ^ (c & 7))) << 4) + ((t0 & 7) << 1)) = w;
            }
        }
        #pragma unroll
        for (int kt = 0; kt < 4; ++kt) {
            bf8_t bh[2];
            #pragma unroll
            for (int cf = 0; cf < 2; ++cf) {
                int c = rb + cf * 16 + (lane & 15);
                int tc = kt * 4 + (lane >> 4);
                bh[cf] = *(const bf8_t*)((const char*)Hs + c * 256 + ((tc ^ (c & 7)) << 4));
            }
            #pragma unroll
            for (int jf = 0; jf < 2; ++jf) {
                int j = jf * 16 + (lane & 15);
                int tc = ch * 16 + kt * 4 + (lane >> 4);
                bf8_t aw = *(const bf8_t*)((const char*)W12s + j * 512 + ((tc ^ (j & 7)) << 4));
                #pragma unroll
                for (int cf = 0; cf < 2; ++cf)
                    acc2[jf][cf] = __builtin_amdgcn_mfma_f32_16x16x32_bf16(aw, bh[cf], acc2[jf][cf], 0, 0, 0);
            }
        }
    }

    #pragma unroll
    for (int jf = 0; jf < 2; ++jf) {
        #pragma unroll
        for (int cf = 0; cf < 2; ++cf) {
            int c = c0 + rb + cf * 16 + (lane & 15);
            #pragma unroll
            for (int i = 0; i < 4; ++i) {
                int j = jf * 16 + ((lane >> 4) << 2) + i;
                if (j < Jn) {
                    size_t off = (size_t)b * (Jn * Cn) + (size_t)j * Cn + c;
                    out[off] = x[off] + acc2[jf][cf][i] + b12[j];
                }
            }
        }
    }
}

// ---------------------------------------------------------------- LN2 over C per (b,j) row; writes xn2 bf16
__global__ __launch_bounds__(256) void ln2_kernel(const float* __restrict__ X2,
        const float* __restrict__ g2, const float* __restrict__ be2,
        u16* __restrict__ xn2)
{
    int row = blockIdx.x * 4 + (threadIdx.x >> 6);
    int lane = threadIdx.x & 63;
    const float* p = X2 + (size_t)row * Cn;
    float4 v0 = ((const float4*)p)[lane];
    float4 v1 = ((const float4*)p)[lane + 64];
    float s = v0.x + v0.y + v0.z + v0.w + v1.x + v1.y + v1.z + v1.w;
    float q = v0.x*v0.x + v0.y*v0.y + v0.z*v0.z + v0.w*v0.w
            + v1.x*v1.x + v1.y*v1.y + v1.z*v1.z + v1.w*v1.w;
    #pragma unroll
    for (int off = 32; off > 0; off >>= 1) { s += __shfl_xor(s, off); q += __shfl_xor(q, off); }
    float mean = s * (1.0f / Cn);
    float var = fmaxf(q * (1.0f / Cn) - mean * mean, 0.f);
    float rs = rsqrtf(var + EPSf);
    float4 ga = ((const float4*)g2)[lane],      ba = ((const float4*)be2)[lane];
    float4 gb = ((const float4*)g2)[lane + 64], bb = ((const float4*)be2)[lane + 64];
    uint2 w0, w1;
    w0.x = pk2((v0.x-mean)*rs*ga.x + ba.x, (v0.y-mean)*rs*ga.y + ba.y);
    w0.y = pk2((v0.z-mean)*rs*ga.z + ba.z, (v0.w-mean)*rs*ga.w + ba.w);
    w1.x = pk2((v1.x-mean)*rs*gb.x + bb.x, (v1.y-mean)*rs*gb.y + bb.y);
    w1.y = pk2((v1.z-mean)*rs*gb.z + bb.z, (v1.w-mean)*rs*gb.w + bb.w);
    ((uint2*)(xn2 + (size_t)row * Cn))[lane] = w0;
    ((uint2*)(xn2 + (size_t)row * Cn))[lane + 64] = w1;
}

// ---------------------------------------------------------------- MFMA GEMM: C(M x N) = A(M x K) * Bt(N x K)^T
// 128x128 tile, BK=32 (R7-proven), 4 waves (2x2), dbuf LDS, chunk-XOR swizzle, N-fast grid
// + bijective XCD-chunk remap (total % 8 == 0). ldOut = output row stride.
// EPI 0: outH = bf16(gelu(acc + bias[col]))
// EPI 1: outF += acc + (bias ? bias[col] : 0)
// EPI 2: outF += acc + bias[(row%17)*512+col]
template<int EPI>
__global__ __launch_bounds__(256) void gemm_bt(
    const u16* __restrict__ A, int ldA,
    const u16* __restrict__ Bt, int ldB,
    int K, int ldOut,
    const float* __restrict__ bias,
    float* __restrict__ outF, u16* __restrict__ outH)
{
    __shared__ __align__(16) u16 As[2][128 * 32];
    __shared__ __align__(16) u16 Bs[2][128 * 32];
    int tid = threadIdx.x;
    int gx = gridDim.x;
    int total = gx * gridDim.y;
    int lid = blockIdx.y * gx + blockIdx.x;
    int cpx = total >> 3;
    int wg = (lid & 7) * cpx + (lid >> 3);     // XCD-chunked remap (total % 8 == 0)
    int n0 = (wg % gx) << 7;
    int m0 = (wg / gx) << 7;

    int wave = tid >> 6, lane = tid & 63;
    int wr = wave >> 1, wc = wave & 1;

    const u16* aSrc[2]; const u16* bSrc[2];
    #pragma unroll
    for (int t = 0; t < 2; ++t) {
        int idx = t * 256 + tid;
        int r = idx >> 2;
        int cs = (idx & 3) ^ ((r >> 1) & 3);
        aSrc[t] = A  + (size_t)(m0 + r) * ldA + cs * 8;
        bSrc[t] = Bt + (size_t)(n0 + r) * ldB + cs * 8;
    }
    int aOff[4], bOff[4];
    #pragma unroll
    for (int i = 0; i < 4; ++i) {
        int ra = wr * 64 + i * 16 + (lane & 15);
        aOff[i] = ra * 64 + ((((lane >> 4)) ^ ((ra >> 1) & 3)) << 4);
        int rb = wc * 64 + i * 16 + (lane & 15);
        bOff[i] = rb * 64 + ((((lane >> 4)) ^ ((rb >> 1) & 3)) << 4);
    }

    f32x4 acc[4][4];
    #pragma unroll
    for (int i = 0; i < 4; ++i)
        #pragma unroll
        for (int j = 0; j < 4; ++j) acc[i][j] = (f32x4)0.f;

    int KT = K >> 5;
    #pragma unroll
    for (int t = 0; t < 2; ++t) {
        int idx = t * 256 + tid;
        gload_lds16(aSrc[t], (char*)&As[0][0] + idx * 16);
        gload_lds16(bSrc[t], (char*)&Bs[0][0] + idx * 16);
    }
    int cur = 0;
    for (int kt = 0; kt < KT; ++kt) {
        asm volatile("s_waitcnt vmcnt(0)" ::: "memory");
        __syncthreads();
        if (kt + 1 < KT) {
            int k0 = (kt + 1) << 5;
            #pragma unroll
            for (int t = 0; t < 2; ++t) {
                int idx = t * 256 + tid;
                gload_lds16(aSrc[t] + k0, (char*)&As[cur ^ 1][0] + idx * 16);
                gload_lds16(bSrc[t] + k0, (char*)&Bs[cur ^ 1][0] + idx * 16);
            }
        }
        bf8_t af[4], bfr[4];
        #pragma unroll
        for (int i = 0; i < 4; ++i) {
            af[i]  = *(const bf8_t*)((const char*)&As[cur][0] + aOff[i]);
            bfr[i] = *(const bf8_t*)((const char*)&Bs[cur][0] + bOff[i]);
        }
        #pragma unroll
        for (int mi = 0; mi < 4; ++mi)
            #pragma unroll
            for (int ni = 0; ni < 4; ++ni)
                acc[mi][ni] = __builtin_amdgcn_mfma_f32_16x16x32_bf16(af[mi], bfr[ni], acc[mi][ni], 0, 0, 0);
        cur ^= 1;
    }

    #pragma unroll
    for (int mi = 0; mi < 4; ++mi) {
        int rbase = m0 + wr * 64 + mi * 16 + ((lane >> 4) << 2);
        #pragma unroll
        for (int ni = 0; ni < 4; ++ni) {
            int col = n0 + wc * 64 + ni * 16 + (lane & 15);
            if (EPI == 0) {
                float bv = bias[col];
                #pragma unroll
                for (int i = 0; i < 4; ++i) {
                    float v = gelu_fast(acc[mi][ni][i] + bv);
                    outH[(size_t)(rbase + i) * ldOut + col] = f2bf(v);
                }
            } else if (EPI == 1) {
                float bv = bias ? bias[col] : 0.f;
                #pragma unroll
                for (int i = 0; i < 4; ++i) {
                    size_t off = (size_t)(rbase + i) * ldOut + col;
                    outF[off] += acc[mi][ni][i] + bv;
                }
            } else {
                #pragma unroll
                for (int i = 0; i < 4; ++i) {
                    int row = rbase + i;
                    int w = row % Jn;
                    size_t off = (size_t)row * ldOut + col;
                    outF[off] += acc[mi][ni][i] + bias[w * Cn + col];
                }
            }
        }
    }
}

// ----------------------------------------------------------------
extern "C" void kernel_launch(void* const* d_in, const int* in_sizes, int n_in,
                              void* d_out, int out_size, void* d_ws, size_t ws_size,
                              hipStream_t stream)
{
    (void)in_sizes; (void)n_in; (void)out_size;
    const float* x   = (const float*)d_in[0];
    const float* adj = (const float*)d_in[1];
    const float* g1  = (const float*)d_in[2];
    const float* be1 = (const float*)d_in[3];
    const float* g2  = (const float*)d_in[4];
    const float* be2 = (const float*)d_in[5];
    const float* Wg1 = (const float*)d_in[6];
    const float* bg1 = (const float*)d_in[7];
    const float* Wg2 = (const float*)d_in[8];
    const float* bg2 = (const float*)d_in[9];
    const float* W11 = (const float*)d_in[10];
    const float* b11 = (const float*)d_in[11];
    const float* W12 = (const float*)d_in[12];
    const float* b12 = (const float*)d_in[13];
    const float* W21 = (const float*)d_in[14];
    const float* b21 = (const float*)d_in[15];
    const float* W22 = (const float*)d_in[16];
    const float* b22 = (const float*)d_in[17];
    float* out = (float*)d_out;

    char* p = (char*)d_ws;
    float* mean1  = (float*)p;                 p += (size_t)Bn * Cn * 4;
    float* rstd1  = (float*)p;                 p += (size_t)Bn * Cn * 4;
    u16*   xn2    = (u16*)p;                   p += (size_t)Mrows * Cn * 2;
    u16*   W21b   = (u16*)p;                   p += (size_t)CHn * Cn * 2;
    u16*   W22b   = (u16*)p;                   p += (size_t)CHn * Cn * 2;
    u16*   Wg1t   = (u16*)p;                   p += (size_t)Cn * Kn * Cn * 2;
    u16*   Wg2t   = (u16*)p;                   p += (size_t)Cn * Kn * Cn * 2;
    u16*   Wcomb  = (u16*)p;                   p += (size_t)Cn * KCAT * 2;
    float* bias2a = (float*)p;                 p += (size_t)Jn * Cn * 4;
    float* bias2b = (float*)p;                 p += (size_t)Jn * Cn * 4;
    float* bias2bc= (float*)p;                 p += (size_t)Jn * Cn * 4;
    u16*   W11p   = (u16*)p;                   p += (size_t)4 * TOKn * 8 * 2;
    u16*   W12p   = (u16*)p;                   p += (size_t)32 * TOKn * 2;
    u16*   xmix   = (u16*)p;                   // big region: stage1 xmix / HX / Hbuf
    u16*   Hbuf   = xmix;

    size_t fixedBytes = (size_t)((char*)xmix - (char*)d_ws);
    bool combined = ws_size >= fixedBytes + (size_t)Mrows * KCAT * 2;
    bool fullH    = ws_size >= fixedBytes + (size_t)Mrows * CHn * 2;

    prep_kernel<<<2562, 256, 0, stream>>>(W21, W22, Wg1, Wg2, bg1, bg2, adj, W11, W12, b22,
                                          W21b, W22b, Wg1t, Wg2t, bias2a, bias2b, bias2bc,
                                          W11p, W12p, Wcomb);
    // stage 1
    premix_kernel<1><<<Bn, 256, 0, stream>>>(x, (const u16*)nullptr, adj, g1, be1, mean1, rstd1,
                                             xmix, Kn * Cn, 0);
    {
        dim3 g(Cn / 128, Bn);
        mlp1_mfma<<<g, 256, 0, stream>>>(x, mean1, rstd1, g1, be1, W11p, b11, W12p, b12, out);
    }
    {
        dim3 g(Cn / 128, Mrows / 128);     // N-fast
        gemm_bt<2><<<g, 256, 0, stream>>>(xmix, Kn * Cn, Wg1t, Kn * Cn, Kn * Cn, Cn, bias2a, out, (u16*)nullptr);
    }
    // stage 2
    ln2_kernel<<<Mrows / 4, 256, 0, stream>>>(out, g2, be2, xn2);
    if (combined) {
        // HX[r] = [ H(2048) | xmix2(1536) ], stride KCAT; one K=3584 GEMM RMWs out.
        u16* HX = xmix;
        {
            dim3 ga(CHn / 128, Mrows / 128);
            gemm_bt<0><<<ga, 256, 0, stream>>>(xn2, Cn, W21b, Cn, Cn, KCAT, b21, (float*)nullptr, HX);
        }
        premix_kernel<2><<<Bn, 256, 0, stream>>>((const float*)nullptr, xn2, adj, (const float*)nullptr,
                                                 (const float*)nullptr, (float*)nullptr, (float*)nullptr,
                                                 HX, KCAT, CHn);
        {
            dim3 g(Cn / 128, Mrows / 128);
            gemm_bt<2><<<g, 256, 0, stream>>>(HX, KCAT, Wcomb, KCAT, KCAT, Cn, bias2bc, out, (u16*)nullptr);
        }
    } else {
        if (fullH) {
            dim3 ga(CHn / 128, Mrows / 128);
            gemm_bt<0><<<ga, 256, 0, stream>>>(xn2, Cn, W21b, Cn, Cn, CHn, b21, (float*)nullptr, Hbuf);
            dim3 gb(Cn / 128, Mrows / 128);
            gemm_bt<1><<<gb, 256, 0, stream>>>(Hbuf, CHn, W22b, CHn, CHn, Cn, b22, out, (u16*)nullptr);
        } else {
            for (int h = 0; h < 2; ++h) {
                int hc = h * 1024;
                dim3 ga(1024 / 128, Mrows / 128);
                gemm_bt<0><<<ga, 256, 0, stream>>>(xn2, Cn, W21b + (size_t)hc * Cn, Cn, Cn, 1024, b21 + hc, (float*)nullptr, Hbuf);
                dim3 gb(Cn / 128, Mrows / 128);
                gemm_bt<1><<<gb, 256, 0, stream>>>(Hbuf, 1024, W22b + hc, CHn, 1024, Cn, (h == 0) ? b22 : (const float*)nullptr, out, (u16*)nullptr);
            }
        }
        premix_kernel<2><<<Bn, 256, 0, stream>>>((const float*)nullptr, xn2, adj, (const float*)nullptr,
                                                 (const float*)nullptr, (float*)nullptr, (float*)nullptr,
                                                 xmix, Kn * Cn, 0);
        {
            dim3 g(Cn / 128, Mrows / 128);
            gemm_bt<2><<<g, 256, 0, stream>>>(xmix, Kn * Cn, Wg2t, Kn * Cn, Kn * Cn, Cn, bias2b, out, (u16*)nullptr);
        }
    }
}

// Round 10
// 1562.508 us; speedup vs baseline: 1.2986x; 1.0468x over previous
//
#include <hip/hip_runtime.h>
#include <hip/hip_bf16.h>

#define Bn   4096
#define Jn   17
#define Cn   512
#define Kn   3
#define TOKn 256
#define CHn  2048
#define EPSf 1e-5f
#define Mrows (Bn * Jn)          // 69632 GEMM rows
#define KCAT (CHn + Kn * Cn)     // 3584 combined K

typedef unsigned short u16;
typedef short bf8_t __attribute__((ext_vector_type(8)));
typedef float f32x4 __attribute__((ext_vector_type(4)));

__device__ __forceinline__ float gelu_fast(float x) {
    float x2 = x * x;
    float z = x * __builtin_fmaf(0.1029474f, x2, 2.3022652f);
    float e = __builtin_amdgcn_exp2f(z);
    float r = __builtin_amdgcn_rcpf(e + 1.0f);
    return x * (1.0f - r);
}
__device__ __forceinline__ float bf2f(u16 u) {
    union { float f; unsigned int i; } w; w.i = ((unsigned int)u) << 16; return w.f;
}
__device__ __forceinline__ u16 f2bf(float f) {
    __hip_bfloat16 h = __float2bfloat16(f);
    union { __hip_bfloat16 h1; u16 u; } cv; cv.h1 = h; return cv.u;
}
__device__ __forceinline__ unsigned pk2(float a, float b) {
    float2 t; t.x = a; t.y = b;
    __hip_bfloat162 h = __float22bfloat162_rn(t);
    union { __hip_bfloat162 h2; unsigned u; } cv; cv.h2 = h; return cv.u;
}
__device__ __forceinline__ void unpack2(unsigned u, float& a, float& b) {
    union { float f; unsigned int i; } t;
    t.i = u << 16;          a = t.f;
    t.i = u & 0xffff0000u;  b = t.f;
}
__device__ __forceinline__ void gload_lds16(const void* g, void* l) {
    __builtin_amdgcn_global_load_lds(
        (const __attribute__((address_space(1))) void*)g,
        (__attribute__((address_space(3))) void*)l, 16, 0, 0);
}

// ---------------------------------------------------------------- prep
__global__ __launch_bounds__(256) void prep_kernel(
    const float* __restrict__ W21, const float* __restrict__ W22,
    const float* __restrict__ Wg1, const float* __restrict__ Wg2,
    const float* __restrict__ bg1, const float* __restrict__ bg2,
    const float* __restrict__ adj,
    const float* __restrict__ W11, const float* __restrict__ W12,
    const float* __restrict__ b22,
    u16* __restrict__ W21b, u16* __restrict__ W22b,
    u16* __restrict__ Wg1t, u16* __restrict__ Wg2t,
    float* __restrict__ bias2a, float* __restrict__ bias2b, float* __restrict__ bias2bc,
    u16* __restrict__ W11p, u16* __restrict__ W12p,
    u16* __restrict__ Wcomb)
{
    int bid = blockIdx.x, tid = threadIdx.x;
    if (bid < 1024) {
        const float* src = (bid < 512) ? W21 : W22;
        u16* dst = (bid < 512) ? W21b : W22b;
        size_t base = (size_t)(bid & 511) * 2048 + (size_t)tid * 8;
        float4 v0 = *(const float4*)(src + base);
        float4 v1 = *(const float4*)(src + base + 4);
        uint4 o;
        o.x = pk2(v0.x, v0.y); o.y = pk2(v0.z, v0.w);
        o.z = pk2(v1.x, v1.y); o.w = pk2(v1.z, v1.w);
        *(uint4*)(dst + base) = o;
    } else if (bid < 2048) {
        const float* src = (bid < 1536) ? Wg1 : Wg2;
        u16* dst = (bid < 1536) ? Wg1t : Wg2t;
        int rbase = ((bid - 1024) & 511) * 3;
        int c = tid * 2;
        for (int rr = 0; rr < 3; ++rr) {
            int ro = rbase + rr;                  // over (k,o)
            int k = ro >> 9, o = ro & 511;
            const float* sp = src + ((size_t)k * Cn + o) * Cn + c;
            float2 v = *(const float2*)sp;
            *(unsigned*)(dst + (size_t)o * (Kn * Cn) + k * Cn + c) = pk2(v.x, v.y);
        }
    } else if (bid == 2048) {
        __shared__ float adjcs[Kn][Jn];
        for (int i = tid; i < Kn * Jn; i += 256) {
            int k = i / Jn, w = i - k * Jn;
            float s = 0.f;
            for (int v = 0; v < Jn; ++v) s += adj[k * (Jn * Jn) + v * Jn + w];
            adjcs[k][w] = s;
        }
        __syncthreads();
        for (int i = tid; i < Jn * Cn; i += 256) {
            int w = i >> 9, o = i & 511;
            float sa = 0.f, sb = 0.f;
            #pragma unroll
            for (int k = 0; k < Kn; ++k) {
                sa += bg1[k * Cn + o] * adjcs[k][w];
                sb += bg2[k * Cn + o] * adjcs[k][w];
            }
            bias2a[i] = sa; bias2b[i] = sb; bias2bc[i] = sb + b22[o];
        }
    } else if (bid == 2049) {
        // W11p: [ck(4)][t(256)][8] = W11[t][ck*8+e], zero-padded k>=17
        for (int i = tid; i < 4 * TOKn * 8; i += 256) {
            int ck = i >> 11, t = (i >> 3) & 255, e = i & 7;
            int k = ck * 8 + e;
            W11p[i] = (k < Jn) ? f2bf(W11[t * Jn + k]) : (u16)0;
        }
        // W12p [32][256] (pad j>=17 rows with 0)
        for (int idx = tid; idx < 32 * TOKn; idx += 256) {
            int j = idx >> 8, t = idx & 255;
            W12p[idx] = (j < Jn) ? f2bf(W12[j * TOKn + t]) : (u16)0;
        }
    } else {
        // Wcomb row o: [0,2048) = W22[o][:], [2048,3584) = Wg2[k][o][c]
        int o = bid - 2050;
        for (int idx = tid; idx < KCAT; idx += 256) {
            float v;
            if (idx < CHn) v = W22[(size_t)o * CHn + idx];
            else {
                int rem = idx - CHn;
                int k = rem >> 9, c = rem & 511;
                v = Wg2[((size_t)k * Cn + o) * Cn + c];
            }
            Wcomb[(size_t)o * KCAT + idx] = f2bf(v);
        }
    }
}

// ---------------------------------------------------------------- premix: (optional LN1) + adjacency mix -> dst[row][k*512+c] bf16
// row = b*17 + w, row stride oStride, column offset oColOff.
template<int STAGE>
__global__ __launch_bounds__(256) void premix_kernel(
    const float* __restrict__ x,          // stage1
    const u16* __restrict__ xn2,          // stage2
    const float* __restrict__ adj,
    const float* __restrict__ g1, const float* __restrict__ be1,
    float* __restrict__ mean1, float* __restrict__ rstd1,
    u16* __restrict__ xmix, int oStride, int oColOff)
{
    __shared__ float xsh[Jn][Cn];
    __shared__ float coef[Kn][Jn][Jn];
    __shared__ float s0sh[Kn][Jn];
    __shared__ float s1sh[Kn][Jn];
    __shared__ float msh[Cn], rsh[Cn];
    int b = blockIdx.x, tid = threadIdx.x;

    for (int i = tid; i < Kn * Jn * Jn; i += 256) {
        int k = i / (Jn * Jn); int rem = i - k * (Jn * Jn);
        int v = rem / Jn; int w = rem - v * Jn;
        float av = adj[i];
        coef[k][w][v] = (STAGE == 1) ? av * g1[v] : av;
    }
    if (STAGE == 1) {
        const float* xp = x + (size_t)b * (Jn * Cn);
        for (int i = tid; i < (Jn * Cn) / 4; i += 256)
            ((float4*)&xsh[0][0])[i] = ((const float4*)xp)[i];
    } else {
        const u16* xp = xn2 + (size_t)b * (Jn * Cn);
        for (int i = tid; i < (Jn * Cn) / 8; i += 256) {
            uint4 u = ((const uint4*)xp)[i];
            float* d = &(&xsh[0][0])[i * 8];
            unpack2(u.x, d[0], d[1]); unpack2(u.y, d[2], d[3]);
            unpack2(u.z, d[4], d[5]); unpack2(u.w, d[6], d[7]);
        }
    }
    __syncthreads();
    if (STAGE == 1) {
        for (int c = tid; c < Cn; c += 256) {
            float s = 0.f, q = 0.f;
            #pragma unroll
            for (int v = 0; v < Jn; ++v) { float t = xsh[v][c]; s += t; q += t * t; }
            float m = s * (1.0f / Jn);
            float var = fmaxf(q * (1.0f / Jn) - m * m, 0.f);
            float r = rsqrtf(var + EPSf);
            msh[c] = m; rsh[c] = r;
            mean1[(size_t)b * Cn + c] = m;
            rstd1[(size_t)b * Cn + c] = r;
        }
    }
    if (tid < Kn * Jn) {
        int k = tid / Jn, w = tid - k * Jn;
        float s0 = 0.f, s1 = 0.f;
        #pragma unroll
        for (int v = 0; v < Jn; ++v) {
            if (STAGE == 1) s0 += adj[k * (Jn * Jn) + v * Jn + w] * be1[v];
            s1 += coef[k][w][v];
        }
        s0sh[k][w] = s0; s1sh[k][w] = s1;
    }
    __syncthreads();
    // vectorized: 2 consecutive c per thread -> u32 pk2 store
    u16* orow = xmix + (size_t)b * Jn * oStride + oColOff;
    int c = tid * 2;
    float m0v = 0.f, m1v = 0.f, r0v = 1.f, r1v = 1.f;
    if (STAGE == 1) { m0v = msh[c]; m1v = msh[c + 1]; r0v = rsh[c]; r1v = rsh[c + 1]; }
    for (int k = 0; k < Kn; ++k)
        for (int w = 0; w < Jn; ++w) {
            float cf[Jn];
            #pragma unroll
            for (int v = 0; v < Jn; ++v) cf[v] = coef[k][w][v];
            float d0 = 0.f, d1 = 0.f;
            #pragma unroll
            for (int v = 0; v < Jn; ++v) { d0 += cf[v] * xsh[v][c]; d1 += cf[v] * xsh[v][c + 1]; }
            float v0, v1;
            if (STAGE == 1) {
                float ss1 = s1sh[k][w], ss0 = s0sh[k][w];
                v0 = r0v * (d0 - m0v * ss1) + ss0;
                v1 = r1v * (d1 - m1v * ss1) + ss0;
            } else { v0 = d0; v1 = d1; }
            *(unsigned*)(orow + (size_t)w * oStride + k * Cn + c) = pk2(v0, v1);
        }
}

// ---------------------------------------------------------------- MLP1 (token mix) via MFMA — 512 threads, 8 waves x 16 c-cols
// Same LDS layouts as R7/R9; per-wave work halves, resident waves/CU double (8 -> 16).
__global__ __launch_bounds__(512) void mlp1_mfma(
    const float* __restrict__ x,
    const float* __restrict__ mean1, const float* __restrict__ rstd1,
    const float* __restrict__ g1, const float* __restrict__ be1,
    const u16* __restrict__ W11p,   // [4][256][8] bf16 padded, k-chunked
    const float* __restrict__ b11,
    const u16* __restrict__ W12p,   // [32][256] bf16 padded
    const float* __restrict__ b12,
    float* __restrict__ out)
{
    __shared__ __align__(16) u16 As[128 * 40];     // xn tile [c][j], stride 80B, swizzled
    __shared__ __align__(16) u16 Hs[128 * 128];    // hidden chunk [c][t], chunk-swizzled
    __shared__ __align__(16) u16 W11s[4 * TOKn * 8]; // [ck][t][8]
    __shared__ __align__(16) u16 W12s[32 * TOKn];
    __shared__ __align__(16) float b11s[TOKn];
    __shared__ __align__(16) float msrs[256];      // [0:128)=mean, [128:256)=rstd
    __shared__ float g1s[32], be1s[32];

    int tid = threadIdx.x;
    int lane = tid & 63, wave = tid >> 6;
    int li = lane & 15, q = lane >> 4;
    int b = blockIdx.y, c0 = blockIdx.x * 128;
    const float* xb = x + (size_t)b * (Jn * Cn);

    // ---- stage (all dests wave-linear for global_load_lds)
    #pragma unroll
    for (int t = 0; t < 2; ++t) {          // W11s: 1024 x 16B, linear
        int idx = t * 512 + tid;
        gload_lds16(W11p + idx * 8, (char*)W11s + idx * 16);
    }
    #pragma unroll
    for (int t = 0; t < 2; ++t) {          // W12s: src chunk s^(row&7)
        int idx = t * 512 + tid;
        int j = idx >> 5, s = idx & 31;
        gload_lds16(W12p + j * TOKn + ((s ^ (j & 7)) << 3), (char*)W12s + idx * 16);
    }
    if (wave == 0) gload_lds16(b11 + lane * 4, (char*)b11s + lane * 16);
    if (wave == 1) {
        const float* src = (lane < 32) ? (mean1 + (size_t)b * Cn + c0 + lane * 4)
                                       : (rstd1 + (size_t)b * Cn + c0 + (lane - 32) * 4);
        gload_lds16(src, (char*)msrs + lane * 16);
    }
    if (tid < Jn) { g1s[tid] = g1[tid]; be1s[tid] = be1[tid]; }
    asm volatile("s_waitcnt vmcnt(0)" ::: "memory");
    __syncthreads();

    // ---- build As[r=c_local][k=j] packed u32 (2 j per thread; pad k>=17 with 0)
    const float* ms = msrs;
    const float* rs = msrs + 128;
    #pragma unroll
    for (int it = 0; it < 4; ++it) {
        int idx = it * 512 + tid;            // 2048: r x 16 j-pairs
        int r = idx & 127, k = (idx >> 7) << 1;
        float mr = ms[r], rr = rs[r];
        float v0 = 0.f, v1 = 0.f;
        if (k < Jn)     v0 = (xb[(size_t)k * Cn + c0 + r] - mr) * rr * g1s[k] + be1s[k];
        if (k + 1 < Jn) v1 = (xb[(size_t)(k + 1) * Cn + c0 + r] - mr) * rr * g1s[k + 1] + be1s[k + 1];
        int ck = (k >> 3) ^ ((r >> 3) & 3);
        *(unsigned*)((char*)As + r * 80 + (ck << 4) + ((k & 7) << 1)) = pk2(v0, v1);
    }
    __syncthreads();

    int wbase = wave * 16;                 // this wave's 16 c-columns
    f32x4 acc2[2];
    acc2[0] = (f32x4)0.f; acc2[1] = (f32x4)0.f;

    bf8_t bfc;
    {
        int c = wbase + li;
        int ck = q ^ ((c >> 3) & 3);
        bfc = *(const bf8_t*)((const char*)As + c * 80 + (ck << 4));
    }

    #pragma unroll
    for (int ch = 0; ch < 2; ++ch) {
        f32x4 acc1[8];
        #pragma unroll
        for (int tf = 0; tf < 8; ++tf) acc1[tf] = (f32x4)0.f;
        #pragma unroll
        for (int tf = 0; tf < 8; ++tf) {
            int t = ch * 128 + tf * 16 + li;
            bf8_t aw = *(const bf8_t*)((const char*)W11s + (q << 12) + t * 16);
            acc1[tf] = __builtin_amdgcn_mfma_f32_16x16x32_bf16(aw, bfc, acc1[tf], 0, 0, 0);
        }
        #pragma unroll
        for (int tf = 0; tf < 8; ++tf) {
            int t0 = tf * 16 + (q << 2);
            float bq0 = b11s[ch * 128 + t0 + 0];
            float bq1 = b11s[ch * 128 + t0 + 1];
            float bq2 = b11s[ch * 128 + t0 + 2];
            float bq3 = b11s[ch * 128 + t0 + 3];
            int c = wbase + li;
            float h0 = gelu_fast(acc1[tf][0] + bq0);
            float h1 = gelu_fast(acc1[tf][1] + bq1);
            float h2 = gelu_fast(acc1[tf][2] + bq2);
            float h3 = gelu_fast(acc1[tf][3] + bq3);
            uint2 w; w.x = pk2(h0, h1); w.y = pk2(h2, h3);
            *(uint2*)((char*)Hs + c * 256 + ((((t0 >> 3) ^ (c & 7))) << 4) + ((t0 & 7) << 1)) = w;
        }
        #pragma unroll
        for (int kt = 0; kt < 4; ++kt) {
            int c = wbase + li;
            int tc = kt * 4 + q;
            bf8_t bh = *(const bf8_t*)((const char*)Hs + c * 256 + ((tc ^ (c & 7)) << 4));
            #pragma unroll
            for (int jf = 0; jf < 2; ++jf) {
                int j = jf * 16 + li;
                int tcg = ch * 16 + kt * 4 + q;
                bf8_t aw = *(const bf8_t*)((const char*)W12s + j * 512 + ((tcg ^ (j & 7)) << 4));
                acc2[jf] = __builtin_amdgcn_mfma_f32_16x16x32_bf16(aw, bh, acc2[jf], 0, 0, 0);
            }
        }
    }

    // ---- epilogue: out[b][j][c] = x + mlp + b12[j]
    #pragma unroll
    for (int jf = 0; jf < 2; ++jf) {
        int c = c0 + wbase + li;
        #pragma unroll
        for (int i = 0; i < 4; ++i) {
            int j = jf * 16 + (q << 2) + i;
            if (j < Jn) {
                size_t off = (size_t)b * (Jn * Cn) + (size_t)j * Cn + c;
                out[off] = x[off] + acc2[jf][i] + b12[j];
            }
        }
    }
}

// ---------------------------------------------------------------- LN2 over C per (b,j) row; writes xn2 bf16
__global__ __launch_bounds__(256) void ln2_kernel(const float* __restrict__ X2,
        const float* __restrict__ g2, const float* __restrict__ be2,
        u16* __restrict__ xn2)
{
    int row = blockIdx.x * 4 + (threadIdx.x >> 6);
    int lane = threadIdx.x & 63;
    const float* p = X2 + (size_t)row * Cn;
    float4 v0 = ((const float4*)p)[lane];
    float4 v1 = ((const float4*)p)[lane + 64];
    float s = v0.x + v0.y + v0.z + v0.w + v1.x + v1.y + v1.z + v1.w;
    float q = v0.x*v0.x + v0.y*v0.y + v0.z*v0.z + v0.w*v0.w
            + v1.x*v1.x + v1.y*v1.y + v1.z*v1.z + v1.w*v1.w;
    #pragma unroll
    for (int off = 32; off > 0; off >>= 1) { s += __shfl_xor(s, off); q += __shfl_xor(q, off); }
    float mean = s * (1.0f / Cn);
    float var = fmaxf(q * (1.0f / Cn) - mean * mean, 0.f);
    float rs = rsqrtf(var + EPSf);
    float4 ga = ((const float4*)g2)[lane],      ba = ((const float4*)be2)[lane];
    float4 gb = ((const float4*)g2)[lane + 64], bb = ((const float4*)be2)[lane + 64];
    uint2 w0, w1;
    w0.x = pk2((v0.x-mean)*rs*ga.x + ba.x, (v0.y-mean)*rs*ga.y + ba.y);
    w0.y = pk2((v0.z-mean)*rs*ga.z + ba.z, (v0.w-mean)*rs*ga.w + ba.w);
    w1.x = pk2((v1.x-mean)*rs*gb.x + bb.x, (v1.y-mean)*rs*gb.y + bb.y);
    w1.y = pk2((v1.z-mean)*rs*gb.z + bb.z, (v1.w-mean)*rs*gb.w + bb.w);
    ((uint2*)(xn2 + (size_t)row * Cn))[lane] = w0;
    ((uint2*)(xn2 + (size_t)row * Cn))[lane + 64] = w1;
}

// ---------------------------------------------------------------- MFMA GEMM: C(M x N) = A(M x K) * Bt(N x K)^T
// 128x128 tile, BK=32 (R7-proven), 4 waves (2x2), dbuf LDS, chunk-XOR swizzle, N-fast grid
// + bijective XCD-chunk remap (total % 8 == 0). ldOut = output row stride.
// EPI 0: outH = bf16(gelu(acc + bias[col]))
// EPI 1: outF += acc + (bias ? bias[col] : 0)
// EPI 2: outF += acc + bias[(row%17)*512+col]
template<int EPI>
__global__ __launch_bounds__(256) void gemm_bt(
    const u16* __restrict__ A, int ldA,
    const u16* __restrict__ Bt, int ldB,
    int K, int ldOut,
    const float* __restrict__ bias,
    float* __restrict__ outF, u16* __restrict__ outH)
{
    __shared__ __align__(16) u16 As[2][128 * 32];
    __shared__ __align__(16) u16 Bs[2][128 * 32];
    int tid = threadIdx.x;
    int gx = gridDim.x;
    int total = gx * gridDim.y;
    int lid = blockIdx.y * gx + blockIdx.x;
    int cpx = total >> 3;
    int wg = (lid & 7) * cpx + (lid >> 3);     // XCD-chunked remap (total % 8 == 0)
    int n0 = (wg % gx) << 7;
    int m0 = (wg / gx) << 7;

    int wave = tid >> 6, lane = tid & 63;
    int wr = wave >> 1, wc = wave & 1;

    const u16* aSrc[2]; const u16* bSrc[2];
    #pragma unroll
    for (int t = 0; t < 2; ++t) {
        int idx = t * 256 + tid;
        int r = idx >> 2;
        int cs = (idx & 3) ^ ((r >> 1) & 3);
        aSrc[t] = A  + (size_t)(m0 + r) * ldA + cs * 8;
        bSrc[t] = Bt + (size_t)(n0 + r) * ldB + cs * 8;
    }
    int aOff[4], bOff[4];
    #pragma unroll
    for (int i = 0; i < 4; ++i) {
        int ra = wr * 64 + i * 16 + (lane & 15);
        aOff[i] = ra * 64 + ((((lane >> 4)) ^ ((ra >> 1) & 3)) << 4);
        int rb = wc * 64 + i * 16 + (lane & 15);
        bOff[i] = rb * 64 + ((((lane >> 4)) ^ ((rb >> 1) & 3)) << 4);
    }

    f32x4 acc[4][4];
    #pragma unroll
    for (int i = 0; i < 4; ++i)
        #pragma unroll
        for (int j = 0; j < 4; ++j) acc[i][j] = (f32x4)0.f;

    int KT = K >> 5;
    #pragma unroll
    for (int t = 0; t < 2; ++t) {
        int idx = t * 256 + tid;
        gload_lds16(aSrc[t], (char*)&As[0][0] + idx * 16);
        gload_lds16(bSrc[t], (char*)&Bs[0][0] + idx * 16);
    }
    int cur = 0;
    for (int kt = 0; kt < KT; ++kt) {
        asm volatile("s_waitcnt vmcnt(0)" ::: "memory");
        __syncthreads();
        if (kt + 1 < KT) {
            int k0 = (kt + 1) << 5;
            #pragma unroll
            for (int t = 0; t < 2; ++t) {
                int idx = t * 256 + tid;
                gload_lds16(aSrc[t] + k0, (char*)&As[cur ^ 1][0] + idx * 16);
                gload_lds16(bSrc[t] + k0, (char*)&Bs[cur ^ 1][0] + idx * 16);
            }
        }
        bf8_t af[4], bfr[4];
        #pragma unroll
        for (int i = 0; i < 4; ++i) {
            af[i]  = *(const bf8_t*)((const char*)&As[cur][0] + aOff[i]);
            bfr[i] = *(const bf8_t*)((const char*)&Bs[cur][0] + bOff[i]);
        }
        #pragma unroll
        for (int mi = 0; mi < 4; ++mi)
            #pragma unroll
            for (int ni = 0; ni < 4; ++ni)
                acc[mi][ni] = __builtin_amdgcn_mfma_f32_16x16x32_bf16(af[mi], bfr[ni], acc[mi][ni], 0, 0, 0);
        cur ^= 1;
    }

    #pragma unroll
    for (int mi = 0; mi < 4; ++mi) {
        int rbase = m0 + wr * 64 + mi * 16 + ((lane >> 4) << 2);
        #pragma unroll
        for (int ni = 0; ni < 4; ++ni) {
            int col = n0 + wc * 64 + ni * 16 + (lane & 15);
            if (EPI == 0) {
                float bv = bias[col];
                #pragma unroll
                for (int i = 0; i < 4; ++i) {
                    float v = gelu_fast(acc[mi][ni][i] + bv);
                    outH[(size_t)(rbase + i) * ldOut + col] = f2bf(v);
                }
            } else if (EPI == 1) {
                float bv = bias ? bias[col] : 0.f;
                #pragma unroll
                for (int i = 0; i < 4; ++i) {
                    size_t off = (size_t)(rbase + i) * ldOut + col;
                    outF[off] += acc[mi][ni][i] + bv;
                }
            } else {
                #pragma unroll
                for (int i = 0; i < 4; ++i) {
                    int row = rbase + i;
                    int w = row % Jn;
                    size_t off = (size_t)row * ldOut + col;
                    outF[off] += acc[mi][ni][i] + bias[w * Cn + col];
                }
            }
        }
    }
}

// ----------------------------------------------------------------
extern "C" void kernel_launch(void* const* d_in, const int* in_sizes, int n_in,
                              void* d_out, int out_size, void* d_ws, size_t ws_size,
                              hipStream_t stream)
{
    (void)in_sizes; (void)n_in; (void)out_size;
    const float* x   = (const float*)d_in[0];
    const float* adj = (const float*)d_in[1];
    const float* g1  = (const float*)d_in[2];
    const float* be1 = (const float*)d_in[3];
    const float* g2  = (const float*)d_in[4];
    const float* be2 = (const float*)d_in[5];
    const float* Wg1 = (const float*)d_in[6];
    const float* bg1 = (const float*)d_in[7];
    const float* Wg2 = (const float*)d_in[8];
    const float* bg2 = (const float*)d_in[9];
    const float* W11 = (const float*)d_in[10];
    const float* b11 = (const float*)d_in[11];
    const float* W12 = (const float*)d_in[12];
    const float* b12 = (const float*)d_in[13];
    const float* W21 = (const float*)d_in[14];
    const float* b21 = (const float*)d_in[15];
    const float* W22 = (const float*)d_in[16];
    const float* b22 = (const float*)d_in[17];
    float* out = (float*)d_out;

    char* p = (char*)d_ws;
    float* mean1  = (float*)p;                 p += (size_t)Bn * Cn * 4;
    float* rstd1  = (float*)p;                 p += (size_t)Bn * Cn * 4;
    u16*   xn2    = (u16*)p;                   p += (size_t)Mrows * Cn * 2;
    u16*   W21b   = (u16*)p;                   p += (size_t)CHn * Cn * 2;
    u16*   W22b   = (u16*)p;                   p += (size_t)CHn * Cn * 2;
    u16*   Wg1t   = (u16*)p;                   p += (size_t)Cn * Kn * Cn * 2;
    u16*   Wg2t   = (u16*)p;                   p += (size_t)Cn * Kn * Cn * 2;
    u16*   Wcomb  = (u16*)p;                   p += (size_t)Cn * KCAT * 2;
    float* bias2a = (float*)p;                 p += (size_t)Jn * Cn * 4;
    float* bias2b = (float*)p;                 p += (size_t)Jn * Cn * 4;
    float* bias2bc= (float*)p;                 p += (size_t)Jn * Cn * 4;
    u16*   W11p   = (u16*)p;                   p += (size_t)4 * TOKn * 8 * 2;
    u16*   W12p   = (u16*)p;                   p += (size_t)32 * TOKn * 2;
    u16*   xmix   = (u16*)p;                   // big region: stage1 xmix / HX / Hbuf
    u16*   Hbuf   = xmix;

    size_t fixedBytes = (size_t)((char*)xmix - (char*)d_ws);
    bool combined = ws_size >= fixedBytes + (size_t)Mrows * KCAT * 2;
    bool fullH    = ws_size >= fixedBytes + (size_t)Mrows * CHn * 2;

    prep_kernel<<<2562, 256, 0, stream>>>(W21, W22, Wg1, Wg2, bg1, bg2, adj, W11, W12, b22,
                                          W21b, W22b, Wg1t, Wg2t, bias2a, bias2b, bias2bc,
                                          W11p, W12p, Wcomb);
    // stage 1
    premix_kernel<1><<<Bn, 256, 0, stream>>>(x, (const u16*)nullptr, adj, g1, be1, mean1, rstd1,
                                             xmix, Kn * Cn, 0);
    {
        dim3 g(Cn / 128, Bn);
        mlp1_mfma<<<g, 512, 0, stream>>>(x, mean1, rstd1, g1, be1, W11p, b11, W12p, b12, out);
    }
    {
        dim3 g(Cn / 128, Mrows / 128);     // N-fast
        gemm_bt<2><<<g, 256, 0, stream>>>(xmix, Kn * Cn, Wg1t, Kn * Cn, Kn * Cn, Cn, bias2a, out, (u16*)nullptr);
    }
    // stage 2
    ln2_kernel<<<Mrows / 4, 256, 0, stream>>>(out, g2, be2, xn2);
    if (combined) {
        // HX[r] = [ H(2048) | xmix2(1536) ], stride KCAT; one K=3584 GEMM RMWs out.
        u16* HX = xmix;
        {
            dim3 ga(CHn / 128, Mrows / 128);
            gemm_bt<0><<<ga, 256, 0, stream>>>(xn2, Cn, W21b, Cn, Cn, KCAT, b21, (float*)nullptr, HX);
        }
        premix_kernel<2><<<Bn, 256, 0, stream>>>((const float*)nullptr, xn2, adj, (const float*)nullptr,
                                                 (const float*)nullptr, (float*)nullptr, (float*)nullptr,
                                                 HX, KCAT, CHn);
        {
            dim3 g(Cn / 128, Mrows / 128);
            gemm_bt<2><<<g, 256, 0, stream>>>(HX, KCAT, Wcomb, KCAT, KCAT, Cn, bias2bc, out, (u16*)nullptr);
        }
    } else {
        if (fullH) {
            dim3 ga(CHn / 128, Mrows / 128);
            gemm_bt<0><<<ga, 256, 0, stream>>>(xn2, Cn, W21b, Cn, Cn, CHn, b21, (float*)nullptr, Hbuf);
            dim3 gb(Cn / 128, Mrows / 128);
            gemm_bt<1><<<gb, 256, 0, stream>>>(Hbuf, CHn, W22b, CHn, CHn, Cn, b22, out, (u16*)nullptr);
        } else {
            for (int h = 0; h < 2; ++h) {
                int hc = h * 1024;
                dim3 ga(1024 / 128, Mrows / 128);
                gemm_bt<0><<<ga, 256, 0, stream>>>(xn2, Cn, W21b + (size_t)hc * Cn, Cn, Cn, 1024, b21 + hc, (float*)nullptr, Hbuf);
                dim3 gb(Cn / 128, Mrows / 128);
                gemm_bt<1><<<gb, 256, 0, stream>>>(Hbuf, 1024, W22b + hc, CHn, 1024, Cn, (h == 0) ? b22 : (const float*)nullptr, out, (u16*)nullptr);
            }
        }
        premix_kernel<2><<<Bn, 256, 0, stream>>>((const float*)nullptr, xn2, adj, (const float*)nullptr,
                                                 (const float*)nullptr, (float*)nullptr, (float*)nullptr,
                                                 xmix, Kn * Cn, 0);
        {
            dim3 g(Cn / 128, Mrows / 128);
            gemm_bt<2><<<g, 256, 0, stream>>>(xmix, Kn * Cn, Wg2t, Kn * Cn, Kn * Cn, Cn, bias2b, out, (u16*)nullptr);
        }
    }
}

// Round 11
// 1549.172 us; speedup vs baseline: 1.3097x; 1.0086x over previous
//
#include <hip/hip_runtime.h>
#include <hip/hip_bf16.h>

#define Bn   4096
#define Jn   17
#define Cn   512
#define Kn   3
#define TOKn 256
#define CHn  2048
#define EPSf 1e-5f
#define Mrows (Bn * Jn)          // 69632 GEMM rows
#define KCAT (CHn + Kn * Cn)     // 3584 combined K

typedef unsigned short u16;
typedef short bf8_t __attribute__((ext_vector_type(8)));
typedef float f32x4 __attribute__((ext_vector_type(4)));

__device__ __forceinline__ float gelu_fast(float x) {
    float x2 = x * x;
    float z = x * __builtin_fmaf(0.1029474f, x2, 2.3022652f);
    float e = __builtin_amdgcn_exp2f(z);
    float r = __builtin_amdgcn_rcpf(e + 1.0f);
    return x * (1.0f - r);
}
__device__ __forceinline__ float bf2f(u16 u) {
    union { float f; unsigned int i; } w; w.i = ((unsigned int)u) << 16; return w.f;
}
__device__ __forceinline__ u16 f2bf(float f) {
    __hip_bfloat16 h = __float2bfloat16(f);
    union { __hip_bfloat16 h1; u16 u; } cv; cv.h1 = h; return cv.u;
}
__device__ __forceinline__ unsigned pk2(float a, float b) {
    float2 t; t.x = a; t.y = b;
    __hip_bfloat162 h = __float22bfloat162_rn(t);
    union { __hip_bfloat162 h2; unsigned u; } cv; cv.h2 = h; return cv.u;
}
__device__ __forceinline__ void unpack2(unsigned u, float& a, float& b) {
    union { float f; unsigned int i; } t;
    t.i = u << 16;          a = t.f;
    t.i = u & 0xffff0000u;  b = t.f;
}
__device__ __forceinline__ void gload_lds16(const void* g, void* l) {
    __builtin_amdgcn_global_load_lds(
        (const __attribute__((address_space(1))) void*)g,
        (__attribute__((address_space(3))) void*)l, 16, 0, 0);
}

// ---------------------------------------------------------------- prep
__global__ __launch_bounds__(256) void prep_kernel(
    const float* __restrict__ W21, const float* __restrict__ W22,
    const float* __restrict__ Wg1, const float* __restrict__ Wg2,
    const float* __restrict__ bg1, const float* __restrict__ bg2,
    const float* __restrict__ adj,
    const float* __restrict__ W11, const float* __restrict__ W12,
    const float* __restrict__ b22,
    u16* __restrict__ W21b, u16* __restrict__ W22b,
    u16* __restrict__ Wg1t, u16* __restrict__ Wg2t,
    float* __restrict__ bias2a, float* __restrict__ bias2b, float* __restrict__ bias2bc,
    u16* __restrict__ W11p, u16* __restrict__ W12p,
    u16* __restrict__ Wcomb)
{
    int bid = blockIdx.x, tid = threadIdx.x;
    if (bid < 1024) {
        const float* src = (bid < 512) ? W21 : W22;
        u16* dst = (bid < 512) ? W21b : W22b;
        size_t base = (size_t)(bid & 511) * 2048 + (size_t)tid * 8;
        float4 v0 = *(const float4*)(src + base);
        float4 v1 = *(const float4*)(src + base + 4);
        uint4 o;
        o.x = pk2(v0.x, v0.y); o.y = pk2(v0.z, v0.w);
        o.z = pk2(v1.x, v1.y); o.w = pk2(v1.z, v1.w);
        *(uint4*)(dst + base) = o;
    } else if (bid < 2048) {
        const float* src = (bid < 1536) ? Wg1 : Wg2;
        u16* dst = (bid < 1536) ? Wg1t : Wg2t;
        int rbase = ((bid - 1024) & 511) * 3;
        int c = tid * 2;
        for (int rr = 0; rr < 3; ++rr) {
            int ro = rbase + rr;                  // over (k,o)
            int k = ro >> 9, o = ro & 511;
            const float* sp = src + ((size_t)k * Cn + o) * Cn + c;
            float2 v = *(const float2*)sp;
            *(unsigned*)(dst + (size_t)o * (Kn * Cn) + k * Cn + c) = pk2(v.x, v.y);
        }
    } else if (bid == 2048) {
        __shared__ float adjcs[Kn][Jn];
        for (int i = tid; i < Kn * Jn; i += 256) {
            int k = i / Jn, w = i - k * Jn;
            float s = 0.f;
            for (int v = 0; v < Jn; ++v) s += adj[k * (Jn * Jn) + v * Jn + w];
            adjcs[k][w] = s;
        }
        __syncthreads();
        for (int i = tid; i < Jn * Cn; i += 256) {
            int w = i >> 9, o = i & 511;
            float sa = 0.f, sb = 0.f;
            #pragma unroll
            for (int k = 0; k < Kn; ++k) {
                sa += bg1[k * Cn + o] * adjcs[k][w];
                sb += bg2[k * Cn + o] * adjcs[k][w];
            }
            bias2a[i] = sa; bias2b[i] = sb; bias2bc[i] = sb + b22[o];
        }
    } else if (bid == 2049) {
        // W11p: [ck(4)][t(256)][8] = W11[t][ck*8+e], zero-padded k>=17
        for (int i = tid; i < 4 * TOKn * 8; i += 256) {
            int ck = i >> 11, t = (i >> 3) & 255, e = i & 7;
            int k = ck * 8 + e;
            W11p[i] = (k < Jn) ? f2bf(W11[t * Jn + k]) : (u16)0;
        }
        // W12p [32][256] (pad j>=17 rows with 0)
        for (int idx = tid; idx < 32 * TOKn; idx += 256) {
            int j = idx >> 8, t = idx & 255;
            W12p[idx] = (j < Jn) ? f2bf(W12[j * TOKn + t]) : (u16)0;
        }
    } else {
        // Wcomb row o: [0,2048) = W22[o][:], [2048,3584) = Wg2[k][o][c]
        int o = bid - 2050;
        for (int idx = tid; idx < KCAT; idx += 256) {
            float v;
            if (idx < CHn) v = W22[(size_t)o * CHn + idx];
            else {
                int rem = idx - CHn;
                int k = rem >> 9, c = rem & 511;
                v = Wg2[((size_t)k * Cn + o) * Cn + c];
            }
            Wcomb[(size_t)o * KCAT + idx] = f2bf(v);
        }
    }
}

// ---------------------------------------------------------------- premix: (optional LN1) + adjacency mix -> dst[row][k*512+c] bf16
// row = b*17 + w, row stride oStride, column offset oColOff.
template<int STAGE>
__global__ __launch_bounds__(256) void premix_kernel(
    const float* __restrict__ x,          // stage1
    const u16* __restrict__ xn2,          // stage2
    const float* __restrict__ adj,
    const float* __restrict__ g1, const float* __restrict__ be1,
    float* __restrict__ mean1, float* __restrict__ rstd1,
    u16* __restrict__ xmix, int oStride, int oColOff)
{
    __shared__ float xsh[Jn][Cn];
    __shared__ float coef[Kn][Jn][Jn];
    __shared__ float s0sh[Kn][Jn];
    __shared__ float s1sh[Kn][Jn];
    __shared__ float msh[Cn], rsh[Cn];
    int b = blockIdx.x, tid = threadIdx.x;

    for (int i = tid; i < Kn * Jn * Jn; i += 256) {
        int k = i / (Jn * Jn); int rem = i - k * (Jn * Jn);
        int v = rem / Jn; int w = rem - v * Jn;
        float av = adj[i];
        coef[k][w][v] = (STAGE == 1) ? av * g1[v] : av;
    }
    if (STAGE == 1) {
        const float* xp = x + (size_t)b * (Jn * Cn);
        for (int i = tid; i < (Jn * Cn) / 4; i += 256)
            ((float4*)&xsh[0][0])[i] = ((const float4*)xp)[i];
    } else {
        const u16* xp = xn2 + (size_t)b * (Jn * Cn);
        for (int i = tid; i < (Jn * Cn) / 8; i += 256) {
            uint4 u = ((const uint4*)xp)[i];
            float* d = &(&xsh[0][0])[i * 8];
            unpack2(u.x, d[0], d[1]); unpack2(u.y, d[2], d[3]);
            unpack2(u.z, d[4], d[5]); unpack2(u.w, d[6], d[7]);
        }
    }
    __syncthreads();
    if (STAGE == 1) {
        for (int c = tid; c < Cn; c += 256) {
            float s = 0.f, q = 0.f;
            #pragma unroll
            for (int v = 0; v < Jn; ++v) { float t = xsh[v][c]; s += t; q += t * t; }
            float m = s * (1.0f / Jn);
            float var = fmaxf(q * (1.0f / Jn) - m * m, 0.f);
            float r = rsqrtf(var + EPSf);
            msh[c] = m; rsh[c] = r;
            mean1[(size_t)b * Cn + c] = m;
            rstd1[(size_t)b * Cn + c] = r;
        }
    }
    if (tid < Kn * Jn) {
        int k = tid / Jn, w = tid - k * Jn;
        float s0 = 0.f, s1 = 0.f;
        #pragma unroll
        for (int v = 0; v < Jn; ++v) {
            if (STAGE == 1) s0 += adj[k * (Jn * Jn) + v * Jn + w] * be1[v];
            s1 += coef[k][w][v];
        }
        s0sh[k][w] = s0; s1sh[k][w] = s1;
    }
    __syncthreads();
    // vectorized: 2 consecutive c per thread -> u32 pk2 store
    u16* orow = xmix + (size_t)b * Jn * oStride + oColOff;
    int c = tid * 2;
    float m0v = 0.f, m1v = 0.f, r0v = 1.f, r1v = 1.f;
    if (STAGE == 1) { m0v = msh[c]; m1v = msh[c + 1]; r0v = rsh[c]; r1v = rsh[c + 1]; }
    for (int k = 0; k < Kn; ++k)
        for (int w = 0; w < Jn; ++w) {
            float cf[Jn];
            #pragma unroll
            for (int v = 0; v < Jn; ++v) cf[v] = coef[k][w][v];
            float d0 = 0.f, d1 = 0.f;
            #pragma unroll
            for (int v = 0; v < Jn; ++v) { d0 += cf[v] * xsh[v][c]; d1 += cf[v] * xsh[v][c + 1]; }
            float v0, v1;
            if (STAGE == 1) {
                float ss1 = s1sh[k][w], ss0 = s0sh[k][w];
                v0 = r0v * (d0 - m0v * ss1) + ss0;
                v1 = r1v * (d1 - m1v * ss1) + ss0;
            } else { v0 = d0; v1 = d1; }
            *(unsigned*)(orow + (size_t)w * oStride + k * Cn + c) = pk2(v0, v1);
        }
}

// ---------------------------------------------------------------- MLP1 (token mix) via MFMA — 512 threads, 8 waves x 16 c-cols
__global__ __launch_bounds__(512) void mlp1_mfma(
    const float* __restrict__ x,
    const float* __restrict__ mean1, const float* __restrict__ rstd1,
    const float* __restrict__ g1, const float* __restrict__ be1,
    const u16* __restrict__ W11p,   // [4][256][8] bf16 padded, k-chunked
    const float* __restrict__ b11,
    const u16* __restrict__ W12p,   // [32][256] bf16 padded
    const float* __restrict__ b12,
    float* __restrict__ out)
{
    __shared__ __align__(16) u16 As[128 * 40];     // xn tile [c][j], stride 80B, swizzled
    __shared__ __align__(16) u16 Hs[128 * 128];    // hidden chunk [c][t], chunk-swizzled
    __shared__ __align__(16) u16 W11s[4 * TOKn * 8]; // [ck][t][8]
    __shared__ __align__(16) u16 W12s[32 * TOKn];
    __shared__ __align__(16) float b11s[TOKn];
    __shared__ __align__(16) float msrs[256];      // [0:128)=mean, [128:256)=rstd
    __shared__ float g1s[32], be1s[32];

    int tid = threadIdx.x;
    int lane = tid & 63, wave = tid >> 6;
    int li = lane & 15, q = lane >> 4;
    int b = blockIdx.y, c0 = blockIdx.x * 128;
    const float* xb = x + (size_t)b * (Jn * Cn);

    // ---- stage (all dests wave-linear for global_load_lds)
    #pragma unroll
    for (int t = 0; t < 2; ++t) {          // W11s: 1024 x 16B, linear
        int idx = t * 512 + tid;
        gload_lds16(W11p + idx * 8, (char*)W11s + idx * 16);
    }
    #pragma unroll
    for (int t = 0; t < 2; ++t) {          // W12s: src chunk s^(row&7)
        int idx = t * 512 + tid;
        int j = idx >> 5, s = idx & 31;
        gload_lds16(W12p + j * TOKn + ((s ^ (j & 7)) << 3), (char*)W12s + idx * 16);
    }
    if (wave == 0) gload_lds16(b11 + lane * 4, (char*)b11s + lane * 16);
    if (wave == 1) {
        const float* src = (lane < 32) ? (mean1 + (size_t)b * Cn + c0 + lane * 4)
                                       : (rstd1 + (size_t)b * Cn + c0 + (lane - 32) * 4);
        gload_lds16(src, (char*)msrs + lane * 16);
    }
    if (tid < Jn) { g1s[tid] = g1[tid]; be1s[tid] = be1[tid]; }
    asm volatile("s_waitcnt vmcnt(0)" ::: "memory");
    __syncthreads();

    // ---- build As[r=c_local][k=j] packed u32 (2 j per thread; pad k>=17 with 0)
    const float* ms = msrs;
    const float* rs = msrs + 128;
    #pragma unroll
    for (int it = 0; it < 4; ++it) {
        int idx = it * 512 + tid;            // 2048: r x 16 j-pairs
        int r = idx & 127, k = (idx >> 7) << 1;
        float mr = ms[r], rr = rs[r];
        float v0 = 0.f, v1 = 0.f;
        if (k < Jn)     v0 = (xb[(size_t)k * Cn + c0 + r] - mr) * rr * g1s[k] + be1s[k];
        if (k + 1 < Jn) v1 = (xb[(size_t)(k + 1) * Cn + c0 + r] - mr) * rr * g1s[k + 1] + be1s[k + 1];
        int ck = (k >> 3) ^ ((r >> 3) & 3);
        *(unsigned*)((char*)As + r * 80 + (ck << 4) + ((k & 7) << 1)) = pk2(v0, v1);
    }
    __syncthreads();

    int wbase = wave * 16;                 // this wave's 16 c-columns
    f32x4 acc2[2];
    acc2[0] = (f32x4)0.f; acc2[1] = (f32x4)0.f;

    bf8_t bfc;
    {
        int c = wbase + li;
        int ck = q ^ ((c >> 3) & 3);
        bfc = *(const bf8_t*)((const char*)As + c * 80 + (ck << 4));
    }

    #pragma unroll
    for (int ch = 0; ch < 2; ++ch) {
        f32x4 acc1[8];
        #pragma unroll
        for (int tf = 0; tf < 8; ++tf) acc1[tf] = (f32x4)0.f;
        #pragma unroll
        for (int tf = 0; tf < 8; ++tf) {
            int t = ch * 128 + tf * 16 + li;
            bf8_t aw = *(const bf8_t*)((const char*)W11s + (q << 12) + t * 16);
            acc1[tf] = __builtin_amdgcn_mfma_f32_16x16x32_bf16(aw, bfc, acc1[tf], 0, 0, 0);
        }
        #pragma unroll
        for (int tf = 0; tf < 8; ++tf) {
            int t0 = tf * 16 + (q << 2);
            float bq0 = b11s[ch * 128 + t0 + 0];
            float bq1 = b11s[ch * 128 + t0 + 1];
            float bq2 = b11s[ch * 128 + t0 + 2];
            float bq3 = b11s[ch * 128 + t0 + 3];
            int c = wbase + li;
            float h0 = gelu_fast(acc1[tf][0] + bq0);
            float h1 = gelu_fast(acc1[tf][1] + bq1);
            float h2 = gelu_fast(acc1[tf][2] + bq2);
            float h3 = gelu_fast(acc1[tf][3] + bq3);
            uint2 w; w.x = pk2(h0, h1); w.y = pk2(h2, h3);
            *(uint2*)((char*)Hs + c * 256 + ((((t0 >> 3) ^ (c & 7))) << 4) + ((t0 & 7) << 1)) = w;
        }
        #pragma unroll
        for (int kt = 0; kt < 4; ++kt) {
            int c = wbase + li;
            int tc = kt * 4 + q;
            bf8_t bh = *(const bf8_t*)((const char*)Hs + c * 256 + ((tc ^ (c & 7)) << 4));
            #pragma unroll
            for (int jf = 0; jf < 2; ++jf) {
                int j = jf * 16 + li;
                int tcg = ch * 16 + kt * 4 + q;
                bf8_t aw = *(const bf8_t*)((const char*)W12s + j * 512 + ((tcg ^ (j & 7)) << 4));
                acc2[jf] = __builtin_amdgcn_mfma_f32_16x16x32_bf16(aw, bh, acc2[jf], 0, 0, 0);
            }
        }
    }

    // ---- epilogue: out[b][j][c] = x + mlp + b12[j]
    #pragma unroll
    for (int jf = 0; jf < 2; ++jf) {
        int c = c0 + wbase + li;
        #pragma unroll
        for (int i = 0; i < 4; ++i) {
            int j = jf * 16 + (q << 2) + i;
            if (j < Jn) {
                size_t off = (size_t)b * (Jn * Cn) + (size_t)j * Cn + c;
                out[off] = x[off] + acc2[jf][i] + b12[j];
            }
        }
    }
}

// ---------------------------------------------------------------- LN2 over C per (b,j) row; writes xn2 bf16
__global__ __launch_bounds__(256) void ln2_kernel(const float* __restrict__ X2,
        const float* __restrict__ g2, const float* __restrict__ be2,
        u16* __restrict__ xn2)
{
    int row = blockIdx.x * 4 + (threadIdx.x >> 6);
    int lane = threadIdx.x & 63;
    const float* p = X2 + (size_t)row * Cn;
    float4 v0 = ((const float4*)p)[lane];
    float4 v1 = ((const float4*)p)[lane + 64];
    float s = v0.x + v0.y + v0.z + v0.w + v1.x + v1.y + v1.z + v1.w;
    float q = v0.x*v0.x + v0.y*v0.y + v0.z*v0.z + v0.w*v0.w
            + v1.x*v1.x + v1.y*v1.y + v1.z*v1.z + v1.w*v1.w;
    #pragma unroll
    for (int off = 32; off > 0; off >>= 1) { s += __shfl_xor(s, off); q += __shfl_xor(q, off); }
    float mean = s * (1.0f / Cn);
    float var = fmaxf(q * (1.0f / Cn) - mean * mean, 0.f);
    float rs = rsqrtf(var + EPSf);
    float4 ga = ((const float4*)g2)[lane],      ba = ((const float4*)be2)[lane];
    float4 gb = ((const float4*)g2)[lane + 64], bb = ((const float4*)be2)[lane + 64];
    uint2 w0, w1;
    w0.x = pk2((v0.x-mean)*rs*ga.x + ba.x, (v0.y-mean)*rs*ga.y + ba.y);
    w0.y = pk2((v0.z-mean)*rs*ga.z + ba.z, (v0.w-mean)*rs*ga.w + ba.w);
    w1.x = pk2((v1.x-mean)*rs*gb.x + bb.x, (v1.y-mean)*rs*gb.y + bb.y);
    w1.y = pk2((v1.z-mean)*rs*gb.z + bb.z, (v1.w-mean)*rs*gb.w + bb.w);
    ((uint2*)(xn2 + (size_t)row * Cn))[lane] = w0;
    ((uint2*)(xn2 + (size_t)row * Cn))[lane + 64] = w1;
}

// ---------------------------------------------------------------- MFMA GEMM: C(M x N) = A(M x K) * Bt(N x K)^T
// 128x128 tile, BK=32, 4 waves (2x2), dbuf LDS, chunk-XOR swizzle, N-fast grid
// + bijective XCD-chunk remap (total % 8 == 0). ldOut = output row stride.
// __launch_bounds__(256, 4): cap regs at 128/wave (64 AGPR acc + <=64 VGPR)
// -> 4 blocks/CU resident (was 3 at VGPR=72), filling the barrier-drain gaps.
// EPI 0: outH = bf16(gelu(acc + bias[col]))
// EPI 1: outF += acc + (bias ? bias[col] : 0)
// EPI 2: outF += acc + bias[(row%17)*512+col]
template<int EPI>
__global__ __launch_bounds__(256, 4) void gemm_bt(
    const u16* __restrict__ A, int ldA,
    const u16* __restrict__ Bt, int ldB,
    int K, int ldOut,
    const float* __restrict__ bias,
    float* __restrict__ outF, u16* __restrict__ outH)
{
    __shared__ __align__(16) u16 As[2][128 * 32];
    __shared__ __align__(16) u16 Bs[2][128 * 32];
    int tid = threadIdx.x;
    int gx = gridDim.x;
    int total = gx * gridDim.y;
    int lid = blockIdx.y * gx + blockIdx.x;
    int cpx = total >> 3;
    int wg = (lid & 7) * cpx + (lid >> 3);     // XCD-chunked remap (total % 8 == 0)
    int n0 = (wg % gx) << 7;
    int m0 = (wg / gx) << 7;

    int wave = tid >> 6, lane = tid & 63;
    int wr = wave >> 1, wc = wave & 1;

    const u16* aSrc[2]; const u16* bSrc[2];
    #pragma unroll
    for (int t = 0; t < 2; ++t) {
        int idx = t * 256 + tid;
        int r = idx >> 2;
        int cs = (idx & 3) ^ ((r >> 1) & 3);
        aSrc[t] = A  + (size_t)(m0 + r) * ldA + cs * 8;
        bSrc[t] = Bt + (size_t)(n0 + r) * ldB + cs * 8;
    }
    int aOff[4], bOff[4];
    #pragma unroll
    for (int i = 0; i < 4; ++i) {
        int ra = wr * 64 + i * 16 + (lane & 15);
        aOff[i] = ra * 64 + ((((lane >> 4)) ^ ((ra >> 1) & 3)) << 4);
        int rb = wc * 64 + i * 16 + (lane & 15);
        bOff[i] = rb * 64 + ((((lane >> 4)) ^ ((rb >> 1) & 3)) << 4);
    }

    f32x4 acc[4][4];
    #pragma unroll
    for (int i = 0; i < 4; ++i)
        #pragma unroll
        for (int j = 0; j < 4; ++j) acc[i][j] = (f32x4)0.f;

    int KT = K >> 5;
    #pragma unroll
    for (int t = 0; t < 2; ++t) {
        int idx = t * 256 + tid;
        gload_lds16(aSrc[t], (char*)&As[0][0] + idx * 16);
        gload_lds16(bSrc[t], (char*)&Bs[0][0] + idx * 16);
    }
    int cur = 0;
    for (int kt = 0; kt < KT; ++kt) {
        asm volatile("s_waitcnt vmcnt(0)" ::: "memory");
        __syncthreads();
        if (kt + 1 < KT) {
            int k0 = (kt + 1) << 5;
            #pragma unroll
            for (int t = 0; t < 2; ++t) {
                int idx = t * 256 + tid;
                gload_lds16(aSrc[t] + k0, (char*)&As[cur ^ 1][0] + idx * 16);
                gload_lds16(bSrc[t] + k0, (char*)&Bs[cur ^ 1][0] + idx * 16);
            }
        }
        bf8_t af[4], bfr[4];
        #pragma unroll
        for (int i = 0; i < 4; ++i) {
            af[i]  = *(const bf8_t*)((const char*)&As[cur][0] + aOff[i]);
            bfr[i] = *(const bf8_t*)((const char*)&Bs[cur][0] + bOff[i]);
        }
        #pragma unroll
        for (int mi = 0; mi < 4; ++mi)
            #pragma unroll
            for (int ni = 0; ni < 4; ++ni)
                acc[mi][ni] = __builtin_amdgcn_mfma_f32_16x16x32_bf16(af[mi], bfr[ni], acc[mi][ni], 0, 0, 0);
        cur ^= 1;
    }

    #pragma unroll
    for (int mi = 0; mi < 4; ++mi) {
        int rbase = m0 + wr * 64 + mi * 16 + ((lane >> 4) << 2);
        #pragma unroll
        for (int ni = 0; ni < 4; ++ni) {
            int col = n0 + wc * 64 + ni * 16 + (lane & 15);
            if (EPI == 0) {
                float bv = bias[col];
                #pragma unroll
                for (int i = 0; i < 4; ++i) {
                    float v = gelu_fast(acc[mi][ni][i] + bv);
                    outH[(size_t)(rbase + i) * ldOut + col] = f2bf(v);
                }
            } else if (EPI == 1) {
                float bv = bias ? bias[col] : 0.f;
                #pragma unroll
                for (int i = 0; i < 4; ++i) {
                    size_t off = (size_t)(rbase + i) * ldOut + col;
                    outF[off] += acc[mi][ni][i] + bv;
                }
            } else {
                #pragma unroll
                for (int i = 0; i < 4; ++i) {
                    int row = rbase + i;
                    int w = row % Jn;
                    size_t off = (size_t)row * ldOut + col;
                    outF[off] += acc[mi][ni][i] + bias[w * Cn + col];
                }
            }
        }
    }
}

// ----------------------------------------------------------------
extern "C" void kernel_launch(void* const* d_in, const int* in_sizes, int n_in,
                              void* d_out, int out_size, void* d_ws, size_t ws_size,
                              hipStream_t stream)
{
    (void)in_sizes; (void)n_in; (void)out_size;
    const float* x   = (const float*)d_in[0];
    const float* adj = (const float*)d_in[1];
    const float* g1  = (const float*)d_in[2];
    const float* be1 = (const float*)d_in[3];
    const float* g2  = (const float*)d_in[4];
    const float* be2 = (const float*)d_in[5];
    const float* Wg1 = (const float*)d_in[6];
    const float* bg1 = (const float*)d_in[7];
    const float* Wg2 = (const float*)d_in[8];
    const float* bg2 = (const float*)d_in[9];
    const float* W11 = (const float*)d_in[10];
    const float* b11 = (const float*)d_in[11];
    const float* W12 = (const float*)d_in[12];
    const float* b12 = (const float*)d_in[13];
    const float* W21 = (const float*)d_in[14];
    const float* b21 = (const float*)d_in[15];
    const float* W22 = (const float*)d_in[16];
    const float* b22 = (const float*)d_in[17];
    float* out = (float*)d_out;

    char* p = (char*)d_ws;
    float* mean1  = (float*)p;                 p += (size_t)Bn * Cn * 4;
    float* rstd1  = (float*)p;                 p += (size_t)Bn * Cn * 4;
    u16*   xn2    = (u16*)p;                   p += (size_t)Mrows * Cn * 2;
    u16*   W21b   = (u16*)p;                   p += (size_t)CHn * Cn * 2;
    u16*   W22b   = (u16*)p;                   p += (size_t)CHn * Cn * 2;
    u16*   Wg1t   = (u16*)p;                   p += (size_t)Cn * Kn * Cn * 2;
    u16*   Wg2t   = (u16*)p;                   p += (size_t)Cn * Kn * Cn * 2;
    u16*   Wcomb  = (u16*)p;                   p += (size_t)Cn * KCAT * 2;
    float* bias2a = (float*)p;                 p += (size_t)Jn * Cn * 4;
    float* bias2b = (float*)p;                 p += (size_t)Jn * Cn * 4;
    float* bias2bc= (float*)p;                 p += (size_t)Jn * Cn * 4;
    u16*   W11p   = (u16*)p;                   p += (size_t)4 * TOKn * 8 * 2;
    u16*   W12p   = (u16*)p;                   p += (size_t)32 * TOKn * 2;
    u16*   xmix   = (u16*)p;                   // big region: stage1 xmix / HX / Hbuf
    u16*   Hbuf   = xmix;

    size_t fixedBytes = (size_t)((char*)xmix - (char*)d_ws);
    bool combined = ws_size >= fixedBytes + (size_t)Mrows * KCAT * 2;
    bool fullH    = ws_size >= fixedBytes + (size_t)Mrows * CHn * 2;

    prep_kernel<<<2562, 256, 0, stream>>>(W21, W22, Wg1, Wg2, bg1, bg2, adj, W11, W12, b22,
                                          W21b, W22b, Wg1t, Wg2t, bias2a, bias2b, bias2bc,
                                          W11p, W12p, Wcomb);
    // stage 1
    premix_kernel<1><<<Bn, 256, 0, stream>>>(x, (const u16*)nullptr, adj, g1, be1, mean1, rstd1,
                                             xmix, Kn * Cn, 0);
    {
        dim3 g(Cn / 128, Bn);
        mlp1_mfma<<<g, 512, 0, stream>>>(x, mean1, rstd1, g1, be1, W11p, b11, W12p, b12, out);
    }
    {
        dim3 g(Cn / 128, Mrows / 128);     // N-fast
        gemm_bt<2><<<g, 256, 0, stream>>>(xmix, Kn * Cn, Wg1t, Kn * Cn, Kn * Cn, Cn, bias2a, out, (u16*)nullptr);
    }
    // stage 2
    ln2_kernel<<<Mrows / 4, 256, 0, stream>>>(out, g2, be2, xn2);
    if (combined) {
        // HX[r] = [ H(2048) | xmix2(1536) ], stride KCAT; one K=3584 GEMM RMWs out.
        u16* HX = xmix;
        {
            dim3 ga(CHn / 128, Mrows / 128);
            gemm_bt<0><<<ga, 256, 0, stream>>>(xn2, Cn, W21b, Cn, Cn, KCAT, b21, (float*)nullptr, HX);
        }
        premix_kernel<2><<<Bn, 256, 0, stream>>>((const float*)nullptr, xn2, adj, (const float*)nullptr,
                                                 (const float*)nullptr, (float*)nullptr, (float*)nullptr,
                                                 HX, KCAT, CHn);
        {
            dim3 g(Cn / 128, Mrows / 128);
            gemm_bt<2><<<g, 256, 0, stream>>>(HX, KCAT, Wcomb, KCAT, KCAT, Cn, bias2bc, out, (u16*)nullptr);
        }
    } else {
        if (fullH) {
            dim3 ga(CHn / 128, Mrows / 128);
            gemm_bt<0><<<ga, 256, 0, stream>>>(xn2, Cn, W21b, Cn, Cn, CHn, b21, (float*)nullptr, Hbuf);
            dim3 gb(Cn / 128, Mrows / 128);
            gemm_bt<1><<<gb, 256, 0, stream>>>(Hbuf, CHn, W22b, CHn, CHn, Cn, b22, out, (u16*)nullptr);
        } else {
            for (int h = 0; h < 2; ++h) {
                int hc = h * 1024;
                dim3 ga(1024 / 128, Mrows / 128);
                gemm_bt<0><<<ga, 256, 0, stream>>>(xn2, Cn, W21b + (size_t)hc * Cn, Cn, Cn, 1024, b21 + hc, (float*)nullptr, Hbuf);
                dim3 gb(Cn / 128, Mrows / 128);
                gemm_bt<1><<<gb, 256, 0, stream>>>(Hbuf, 1024, W22b + hc, CHn, 1024, Cn, (h == 0) ? b22 : (const float*)nullptr, out, (u16*)nullptr);
            }
        }
        premix_kernel<2><<<Bn, 256, 0, stream>>>((const float*)nullptr, xn2, adj, (const float*)nullptr,
                                                 (const float*)nullptr, (float*)nullptr, (float*)nullptr,
                                                 xmix, Kn * Cn, 0);
        {
            dim3 g(Cn / 128, Mrows / 128);
            gemm_bt<2><<<g, 256, 0, stream>>>(xmix, Kn * Cn, Wg2t, Kn * Cn, Kn * Cn, Cn, bias2b, out, (u16*)nullptr);
        }
    }
}